// Round 10
// baseline (512.903 us; speedup 1.0000x reference)
//
#include <hip/hip_runtime.h>
#include <hip/hip_cooperative_groups.h>
#include <math.h>

namespace cg = cooperative_groups;

// Problem: b=2, h=8, n=1024, d=64, DIM=512. Inputs/outputs FLOAT32.
// Internal pipeline bf16 MFMA (f32 accumulate). SCALE = 1/8.
// Primary: single cooperative kernel (512 blocks, 2/CU) with grid.sync().
// Fallback (if cooperative launch rejected): the R8 6-kernel sequence.

typedef __bf16 bf16x8 __attribute__((ext_vector_type(8)));
typedef float f32x4 __attribute__((ext_vector_type(4)));

#define SCALE 0.125f
#define GRID 512

#define GLL(g, l) __builtin_amdgcn_global_load_lds(                         \
    (const __attribute__((address_space(1))) void*)(g),                     \
    (__attribute__((address_space(3))) void*)(l), 16, 0, 0)

__device__ __forceinline__ unsigned short f2bf(float f){
  unsigned int x = __builtin_bit_cast(unsigned int, f);
  unsigned int r = (x + 0x7fffu + ((x >> 16) & 1u)) >> 16;  // RNE
  return (unsigned short)r;
}
__device__ __forceinline__ float bf2f(unsigned short u){
  unsigned int x = ((unsigned int)u) << 16;
  return __builtin_bit_cast(float, x);
}
__device__ __forceinline__ f32x4 mfma16(bf16x8 a, bf16x8 b, f32x4 c){
  return __builtin_amdgcn_mfma_f32_16x16x32_bf16(a, b, c, 0, 0, 0);
}
__device__ __forceinline__ bf16x8 ld8(const unsigned short* p){
  return *(const bf16x8*)p;
}

// ===================== device phase helpers (shared by both paths) ==========

__device__ __forceinline__ void phase_prep_item(
    int it, int t, const float* x,
    const float* w0, const float* w1, const float* w2, const float* w3,
    const float* w4, const float* w5, const float* w6,
    unsigned short* xb, unsigned short* wT, unsigned char* smem){
  if (it < 1024){
    int i = it * 256 + t;
    float4 v = ((const float4*)x)[i];
    ushort4 o; o.x = f2bf(v.x); o.y = f2bf(v.y); o.z = f2bf(v.z); o.w = f2bf(v.w);
    ((ushort4*)xb)[i] = o;
    return;
  }
  float* lds = (float*)smem;                 // 64*65*4 = 16640 B
  int bx = it - 1024;
  int mat = bx >> 6, tile = bx & 63, tr = tile >> 3, tc = tile & 7;
  int k0 = tr * 64, c0 = tc * 64;
  const float* src;
  switch (mat){
    case 0: src = w0; break; case 1: src = w1; break; case 2: src = w2; break;
    case 3: src = w3; break; case 4: src = w4; break; case 5: src = w5; break;
    default: src = w6; break;
  }
#pragma unroll
  for (int i = 0; i < 4; ++i){
    int r = (t >> 4) + i * 16, c4 = (t & 15) * 4;
    float4 v = *(const float4*)(src + (size_t)(k0 + r) * 512 + c0 + c4);
    lds[r * 65 + c4 + 0] = v.x; lds[r * 65 + c4 + 1] = v.y;
    lds[r * 65 + c4 + 2] = v.z; lds[r * 65 + c4 + 3] = v.w;
  }
  __syncthreads();
  unsigned short* dst = wT + (size_t)mat * 262144;
#pragma unroll
  for (int i = 0; i < 4; ++i){
    int oc = (t >> 4) + i * 16;
    int kq = (t & 15) * 4;
    ushort4 o;
    o.x = f2bf(lds[(kq + 0) * 65 + oc]);
    o.y = f2bf(lds[(kq + 1) * 65 + oc]);
    o.z = f2bf(lds[(kq + 2) * 65 + oc]);
    o.w = f2bf(lds[(kq + 3) * 65 + oc]);
    *(ushort4*)(dst + (size_t)(c0 + oc) * 512 + k0 + kq) = o;
  }
  __syncthreads();
}

__device__ __forceinline__ void phase_proj_item(
    int it, int t, const unsigned short* xb, const unsigned short* wT,
    unsigned short* P, unsigned char* smem){
  unsigned short* sA = (unsigned short*)smem;
  unsigned short* sB = sA + 128 * 32;
  int lane = t & 63, l16 = lane & 15, quad = lane >> 4;
  int w = t >> 6, wm = w >> 1, wn = w & 1;
  int srow = lane >> 2, scol = (lane & 3) * 8;
  int mt = it / 24, nt = it - mt * 24;
  int M0 = mt * 128, N0 = nt * 128;
  int matb = N0 >> 9;
  int nin = N0 & 511;
  const unsigned short* gA = xb + (size_t)(M0 + w*32 + srow) * 512 + scol;
  const unsigned short* gB = wT + (size_t)matb * 262144
                               + (size_t)(nin + w*32 + srow) * 512 + scol;
  unsigned short* lA = sA + (w*32) * 32;
  unsigned short* lB = sB + (w*32) * 32;
  f32x4 acc[4][4] = {};
  for (int k0 = 0; k0 < 512; k0 += 32){
    GLL(gA + k0,            lA);
    GLL(gA + k0 + 16*512,   lA + 16*32);
    GLL(gB + k0,            lB);
    GLL(gB + k0 + 16*512,   lB + 16*32);
    __syncthreads();
    bf16x8 aw[4], ax[4];
#pragma unroll
    for (int fi = 0; fi < 4; ++fi)
      aw[fi] = *(const bf16x8*)(sB + (wn*64 + fi*16 + l16) * 32 + quad * 8);
#pragma unroll
    for (int mi = 0; mi < 4; ++mi)
      ax[mi] = *(const bf16x8*)(sA + (wm*64 + mi*16 + l16) * 32 + quad * 8);
#pragma unroll
    for (int fi = 0; fi < 4; ++fi)
#pragma unroll
      for (int mi = 0; mi < 4; ++mi)
        acc[fi][mi] = mfma16(aw[fi], ax[mi], acc[fi][mi]);
    __syncthreads();
  }
#pragma unroll
  for (int fi = 0; fi < 4; ++fi)
#pragma unroll
    for (int mi = 0; mi < 4; ++mi){
      int row = M0 + wm*64 + mi*16 + l16;
      int b_ = row >> 10, n_ = row & 1023;
      int c0 = N0 + wn*64 + fi*16 + quad*4;
      int h = (c0 & 511) >> 6, d = c0 & 63;
      int bh = b_*8 + h;
      ushort4 o;
      o.x = f2bf(acc[fi][mi][0]); o.y = f2bf(acc[fi][mi][1]);
      o.z = f2bf(acc[fi][mi][2]); o.w = f2bf(acc[fi][mi][3]);
      *(ushort4*)(P + (size_t)(matb*16 + bh) * 65536 + (size_t)n_ * 64 + d) = o;
    }
}

__device__ __forceinline__ void phase_qkvct_item(
    int it, int t, const unsigned short* P,
    unsigned short* term1, unsigned short* sig, unsigned short* vcT,
    unsigned char* smem){
  if (it < 256){
    unsigned short* lds = (unsigned short*)smem;    // 64*72*2 = 9216 B
    int bh = it >> 4, nt = it & 15;
    int N0 = nt * 64;
    const unsigned short* src = P + (size_t)(5*16 + bh) * 65536 + (size_t)N0 * 64;
#pragma unroll
    for (int i2 = 0; i2 < 2; ++i2){
      int id = i2 * 256 + t;
      int r = id >> 3, c8 = (id & 7) * 8;
      ushort4 v0 = *(const ushort4*)(src + r * 64 + c8);
      ushort4 v1 = *(const ushort4*)(src + r * 64 + c8 + 4);
      *(ushort4*)(lds + r * 72 + c8) = v0;
      *(ushort4*)(lds + r * 72 + c8 + 4) = v1;
    }
    __syncthreads();
    unsigned short* dst = vcT + (size_t)bh * 65536;
#pragma unroll
    for (int i2 = 0; i2 < 2; ++i2){
      int id = i2 * 256 + t;
      int dd = id >> 3, n8 = (id & 7) * 8;
      ushort4 a, b;
      a.x = lds[(n8+0)*72 + dd]; a.y = lds[(n8+1)*72 + dd];
      a.z = lds[(n8+2)*72 + dd]; a.w = lds[(n8+3)*72 + dd];
      b.x = lds[(n8+4)*72 + dd]; b.y = lds[(n8+5)*72 + dd];
      b.z = lds[(n8+6)*72 + dd]; b.w = lds[(n8+7)*72 + dd];
      *(ushort4*)(dst + (size_t)dd * 1024 + N0 + n8) = a;
      *(ushort4*)(dst + (size_t)dd * 1024 + N0 + n8 + 4) = b;
    }
    __syncthreads();
    return;
  }
  unsigned short* sA = (unsigned short*)smem;
  unsigned short* sB = sA + 128 * 32;
  int id = it - 256;
  int bh = id & 15, tt = id >> 4;
  int mat = (tt >= 36);
  int tl = mat ? tt - 36 : tt;
  int ti = 0;
  while (tl >= ti + 1){ tl -= ti + 1; ++ti; }
  int tj = tl;
  int R0, C0;
  const unsigned short *Asrc, *Bsrc;
  if (!mat){ R0 = ti * 128; C0 = tj * 128;
             Asrc = P + (size_t)(3*16 + bh) * 65536;
             Bsrc = P + (size_t)(2*16 + bh) * 65536; }
  else     { R0 = tj * 128; C0 = ti * 128;
             Asrc = P + (size_t)(0*16 + bh) * 65536;
             Bsrc = P + (size_t)(1*16 + bh) * 65536; }
  int lane = t & 63, l16 = lane & 15, quad = lane >> 4;
  int w = t >> 6, wm = w >> 1, wn = w & 1;
  int srow = lane >> 2, scol = (lane & 3) * 8;
  const unsigned short* gA = Asrc + (size_t)(R0 + w*32 + srow) * 64 + scol;
  const unsigned short* gB = Bsrc + (size_t)(C0 + w*32 + srow) * 64 + scol;
  unsigned short* lA = sA + (w*32) * 32;
  unsigned short* lB = sB + (w*32) * 32;
  f32x4 acc[4][4] = {};
#pragma unroll
  for (int k0 = 0; k0 < 64; k0 += 32){
    GLL(gA + k0,           lA);
    GLL(gA + k0 + 16*64,   lA + 16*32);
    GLL(gB + k0,           lB);
    GLL(gB + k0 + 16*64,   lB + 16*32);
    __syncthreads();
    bf16x8 af[4], bfr[4];
#pragma unroll
    for (int mi = 0; mi < 4; ++mi)
      af[mi] = *(const bf16x8*)(sA + (wm*64 + mi*16 + l16) * 32 + quad * 8);
#pragma unroll
    for (int fi = 0; fi < 4; ++fi)
      bfr[fi] = *(const bf16x8*)(sB + (wn*64 + fi*16 + l16) * 32 + quad * 8);
#pragma unroll
    for (int fi = 0; fi < 4; ++fi)
#pragma unroll
      for (int mi = 0; mi < 4; ++mi)
        acc[fi][mi] = mfma16(bfr[fi], af[mi], acc[fi][mi]);
    __syncthreads();
  }
  unsigned short* outp = (mat ? sig : term1) + (size_t)bh * 1048576;
#pragma unroll
  for (int fi = 0; fi < 4; ++fi)
#pragma unroll
    for (int mi = 0; mi < 4; ++mi){
      int row = R0 + wm*64 + mi*16 + l16;
      int c0 = C0 + wn*64 + fi*16 + quad*4;
      ushort4 o;
#pragma unroll
      for (int r = 0; r < 4; ++r){
        int col = c0 + r;
        float v = acc[fi][mi][r] * SCALE;
        unsigned short res;
        if (!mat) res = (col <= row) ? f2bf(v) : (unsigned short)0;
        else      res = (col >  row) ? f2bf(1.f / (1.f + expf(-v))) : (unsigned short)0;
        ((unsigned short*)&o)[r] = res;
      }
      *(ushort4*)(outp + (size_t)row * 1024 + c0) = o;
    }
}

__device__ __forceinline__ void phase_scores_item(
    int it, int t, const unsigned short* P, const unsigned short* term1,
    const unsigned short* sig, unsigned short* finb, unsigned char* smem){
  unsigned short* sA = (unsigned short*)smem;
  unsigned short* sB = sA + 128 * 32;
  int bh = it & 15, tt = it >> 4;
  int k = 1, T = 0;
  while (tt >= T + k){ T += k; ++k; }
  int delta = 8 - k;
  int tj = tt - T, ti = tj + delta;
  int M0 = ti * 128, N0 = tj * 128;
  size_t sbase = (size_t)bh * 1048576;
  int lane = t & 63, l16 = lane & 15, quad = lane >> 4;
  int w = t >> 6, wm = w >> 1, wn = w & 1;
  int srow = lane >> 2, scol = (lane & 3) * 8;
  unsigned short* lA = sA + (w*32) * 32;
  unsigned short* lB = sB + (w*32) * 32;
  f32x4 acc_u[4][4] = {};
  f32x4 acc_c[4][4] = {};
  {
    const unsigned short* gA = term1 + sbase + (size_t)(M0 + w*32 + srow) * 1024 + scol;
    const unsigned short* gB = sig   + sbase + (size_t)(N0 + w*32 + srow) * 1024 + scol;
    int steps = (delta + 1) * 4;
    for (int s = 0; s < steps; ++s){
      int j0 = N0 + s * 32;
      GLL(gA + j0,             lA);
      GLL(gA + j0 + 16*1024,   lA + 16*32);
      GLL(gB + j0,             lB);
      GLL(gB + j0 + 16*1024,   lB + 16*32);
      __syncthreads();
      bf16x8 af[4], bfr[4];
#pragma unroll
      for (int mi = 0; mi < 4; ++mi)
        af[mi] = *(const bf16x8*)(sA + (wm*64 + mi*16 + l16) * 32 + quad * 8);
#pragma unroll
      for (int fi = 0; fi < 4; ++fi)
        bfr[fi] = *(const bf16x8*)(sB + (wn*64 + fi*16 + l16) * 32 + quad * 8);
#pragma unroll
      for (int fi = 0; fi < 4; ++fi)
#pragma unroll
        for (int mi = 0; mi < 4; ++mi)
          acc_u[fi][mi] = mfma16(bfr[fi], af[mi], acc_u[fi][mi]);
      __syncthreads();
    }
  }
  {
    const unsigned short* Qc = P + (size_t)(3*16 + bh) * 65536;
    const unsigned short* Kc = P + (size_t)(4*16 + bh) * 65536;
#pragma unroll
    for (int k0 = 0; k0 < 64; k0 += 32){
      bf16x8 af[4], bfr[4];
#pragma unroll
      for (int mi = 0; mi < 4; ++mi)
        af[mi] = ld8(Qc + (size_t)(M0 + wm*64 + mi*16 + l16) * 64 + k0 + quad * 8);
#pragma unroll
      for (int fi = 0; fi < 4; ++fi)
        bfr[fi] = ld8(Kc + (size_t)(N0 + wn*64 + fi*16 + l16) * 64 + k0 + quad * 8);
#pragma unroll
      for (int fi = 0; fi < 4; ++fi)
#pragma unroll
        for (int mi = 0; mi < 4; ++mi)
          acc_c[fi][mi] = mfma16(bfr[fi], af[mi], acc_c[fi][mi]);
    }
  }
  unsigned short* outp = finb + sbase;
#pragma unroll
  for (int fi = 0; fi < 4; ++fi)
#pragma unroll
    for (int mi = 0; mi < 4; ++mi){
      int row = M0 + wm*64 + mi*16 + l16;
      int c0 = N0 + wn*64 + fi*16 + quad*4;
      ushort4 o;
#pragma unroll
      for (int r = 0; r < 4; ++r){
        float su = acc_u[fi][mi][r];
        float v = acc_c[fi][mi][r] * SCALE - su / (1.f + expf(-su));
        ((unsigned short*)&o)[r] = f2bf(v);
      }
      *(ushort4*)(outp + (size_t)row * 1024 + c0) = o;
    }
}

__device__ __forceinline__ void phase_pvsoft_item(
    int it, int t, const unsigned short* finb, const unsigned short* vcT,
    unsigned short* O, unsigned char* smem){
  unsigned short* lp = (unsigned short*)smem;     // probs [16][1032]
  float* red = (float*)smem;                      // overlay
  int bh = it & 15, mt = 63 - (it >> 4);
  int m0 = mt * 16;
  int kceil = ((m0 + 16 + 31) >> 5) << 5;
  {
    int rl = t >> 4, sub = t & 15;
    int rloc = m0 + rl;
    const unsigned short* p = finb + (size_t)bh * 1048576 + (size_t)rloc * 1024;
    float v[8][8];
    float m = -INFINITY;
#pragma unroll
    for (int i = 0; i < 8; ++i){
      int c8 = (sub + 16*i) * 8;
      if (c8 < kceil){
        ushort4 u0 = *(const ushort4*)(p + c8);
        ushort4 u1 = *(const ushort4*)(p + c8 + 4);
        float vv[8] = {bf2f(u0.x), bf2f(u0.y), bf2f(u0.z), bf2f(u0.w),
                       bf2f(u1.x), bf2f(u1.y), bf2f(u1.z), bf2f(u1.w)};
#pragma unroll
        for (int e = 0; e < 8; ++e){
          v[i][e] = (c8 + e <= rloc) ? vv[e] : -INFINITY;
          m = fmaxf(m, v[i][e]);
        }
      }
    }
#pragma unroll
    for (int off = 1; off < 16; off <<= 1) m = fmaxf(m, __shfl_xor(m, off));
    float s = 0.f;
#pragma unroll
    for (int i = 0; i < 8; ++i){
      int c8 = (sub + 16*i) * 8;
      if (c8 < kceil){
#pragma unroll
        for (int e = 0; e < 8; ++e){
          v[i][e] = expf(v[i][e] - m);
          s += v[i][e];
        }
      }
    }
#pragma unroll
    for (int off = 1; off < 16; off <<= 1) s += __shfl_xor(s, off);
    float inv = 1.f / s;
#pragma unroll
    for (int i = 0; i < 8; ++i){
      int c8 = (sub + 16*i) * 8;
      if (c8 < kceil){
        ushort4 o0, o1;
        o0.x = f2bf(v[i][0] * inv); o0.y = f2bf(v[i][1] * inv);
        o0.z = f2bf(v[i][2] * inv); o0.w = f2bf(v[i][3] * inv);
        o1.x = f2bf(v[i][4] * inv); o1.y = f2bf(v[i][5] * inv);
        o1.z = f2bf(v[i][6] * inv); o1.w = f2bf(v[i][7] * inv);
        *(ushort4*)(lp + rl * 1032 + c8) = o0;
        *(ushort4*)(lp + rl * 1032 + c8 + 4) = o1;
      }
    }
  }
  __syncthreads();
  int lane = t & 63, l16 = lane & 15, quad = lane >> 4, w = t >> 6;
  const unsigned short* Bt = vcT + (size_t)bh * 65536;
  int ktot = kceil >> 5;
  int per = (ktot + 3) >> 2;
  int s0 = w * per, s1 = min(s0 + per, ktot);
  f32x4 acc[4] = {};
  for (int s = s0; s < s1; ++s){
    int k0 = s * 32;
    bf16x8 a = *(const bf16x8*)(lp + l16 * 1032 + k0 + quad * 8);
#pragma unroll
    for (int fi = 0; fi < 4; ++fi){
      bf16x8 b = ld8(Bt + (size_t)(fi*16 + l16) * 1024 + k0 + quad * 8);
      acc[fi] = mfma16(a, b, acc[fi]);
    }
  }
  __syncthreads();
#pragma unroll
  for (int fi = 0; fi < 4; ++fi)
#pragma unroll
    for (int r = 0; r < 4; ++r)
      red[w * 1024 + (quad*4 + r) * 64 + fi*16 + l16] = acc[fi][r];
  __syncthreads();
  float4 a0 = ((const float4*)(red + 0*1024))[t];
  float4 a1 = ((const float4*)(red + 1*1024))[t];
  float4 a2 = ((const float4*)(red + 2*1024))[t];
  float4 a3 = ((const float4*)(red + 3*1024))[t];
  ushort4 o;
  o.x = f2bf(a0.x + a1.x + a2.x + a3.x);
  o.y = f2bf(a0.y + a1.y + a2.y + a3.y);
  o.z = f2bf(a0.z + a1.z + a2.z + a3.z);
  o.w = f2bf(a0.w + a1.w + a2.w + a3.w);
  int e = t * 4, row = e >> 6, col = e & 63;
  *(ushort4*)(O + (size_t)bh * 65536 + (size_t)(m0 + row) * 64 + col) = o;
  __syncthreads();
}

__device__ __forceinline__ void phase_out_item(
    int it, int t, const unsigned short* O, const unsigned short* woT,
    float* out, unsigned char* smem){
  float* red = (float*)smem;
  int lane = t & 63, l16 = lane & 15, quad = lane >> 4, w = t >> 6;
  int mt = it >> 3, nt = it & 7;
  int m0 = mt * 16, n0 = nt * 64;
  int r_ = m0 + l16, b_ = r_ >> 10, n_ = r_ & 1023;
  f32x4 acc[4] = {};
#pragma unroll
  for (int s = 0; s < 4; ++s){
    int kk = w * 128 + s * 32 + quad * 8;
    int h = kk >> 6, dd = kk & 63;
    bf16x8 a = ld8(O + (size_t)(b_*8 + h) * 65536 + (size_t)n_ * 64 + dd);
#pragma unroll
    for (int fi = 0; fi < 4; ++fi){
      bf16x8 b = ld8(woT + (size_t)(n0 + fi*16 + l16) * 512 + kk);
      acc[fi] = mfma16(a, b, acc[fi]);
    }
  }
#pragma unroll
  for (int fi = 0; fi < 4; ++fi)
#pragma unroll
    for (int r = 0; r < 4; ++r)
      red[w * 1024 + (quad*4 + r) * 64 + fi*16 + l16] = acc[fi][r];
  __syncthreads();
  float4 a0 = ((const float4*)(red + 0*1024))[t];
  float4 a1 = ((const float4*)(red + 1*1024))[t];
  float4 a2 = ((const float4*)(red + 2*1024))[t];
  float4 a3 = ((const float4*)(red + 3*1024))[t];
  float4 o;
  o.x = a0.x + a1.x + a2.x + a3.x;
  o.y = a0.y + a1.y + a2.y + a3.y;
  o.z = a0.z + a1.z + a2.z + a3.z;
  o.w = a0.w + a1.w + a2.w + a3.w;
  int e = t * 4, row = e >> 6, col = e & 63;
  *(float4*)(out + (size_t)(m0 + row) * 512 + n0 + col) = o;
  __syncthreads();
}

// ===================== cooperative mega-kernel ==============================
__global__ __launch_bounds__(256, 2) void k_all(
    const float* __restrict__ x,
    const float* __restrict__ w0, const float* __restrict__ w1,
    const float* __restrict__ w2, const float* __restrict__ w3,
    const float* __restrict__ w4, const float* __restrict__ w5,
    const float* __restrict__ w6,
    float* __restrict__ out, unsigned short* __restrict__ ws){
  cg::grid_group grid = cg::this_grid();
  __shared__ __align__(16) unsigned char smem[33024];
  unsigned short* wT    = ws;
  unsigned short* xb    = wT    + (size_t)7  * 262144;
  unsigned short* P     = xb    + (size_t)1048576;
  unsigned short* vcT   = P     + (size_t)96 * 65536;
  unsigned short* term1 = vcT   + (size_t)16 * 65536;
  unsigned short* sig   = term1 + (size_t)16 * 1048576;
  unsigned short* O     = sig   + (size_t)16 * 1048576;
  unsigned short* finb  = O     + (size_t)16 * 65536;
  int t = threadIdx.x;

  for (int it = blockIdx.x; it < 1472; it += GRID)
    phase_prep_item(it, t, x, w0, w1, w2, w3, w4, w5, w6, xb, wT, smem);
  grid.sync();
  for (int it = blockIdx.x; it < 384; it += GRID)
    phase_proj_item(it, t, xb, wT, P, smem);
  grid.sync();
  for (int it = blockIdx.x; it < 1408; it += GRID)
    phase_qkvct_item(it, t, P, term1, sig, vcT, smem);
  grid.sync();
  for (int it = blockIdx.x; it < 576; it += GRID)
    phase_scores_item(it, t, P, term1, sig, finb, smem);
  grid.sync();
  for (int it = blockIdx.x; it < 1024; it += GRID)
    phase_pvsoft_item(it, t, finb, vcT, O, smem);
  grid.sync();
  const unsigned short* woT = wT + (size_t)6 * 262144;
  for (int it = blockIdx.x; it < 1024; it += GRID)
    phase_out_item(it, t, O, woT, out, smem);
}

// ===================== fallback kernels (R8 sequence) =======================
__global__ __launch_bounds__(256) void k_prep(
    const float* __restrict__ x,
    const float* __restrict__ w0, const float* __restrict__ w1,
    const float* __restrict__ w2, const float* __restrict__ w3,
    const float* __restrict__ w4, const float* __restrict__ w5,
    const float* __restrict__ w6,
    unsigned short* __restrict__ xb, unsigned short* __restrict__ wT){
  __shared__ __align__(16) unsigned char smem[16640];
  phase_prep_item(blockIdx.x, threadIdx.x, x, w0, w1, w2, w3, w4, w5, w6,
                  xb, wT, smem);
}
__global__ __launch_bounds__(256) void k_proj(
    const unsigned short* __restrict__ xb, const unsigned short* __restrict__ wT,
    unsigned short* __restrict__ P){
  __shared__ __align__(16) unsigned char smem[16384];
  phase_proj_item(blockIdx.x, threadIdx.x, xb, wT, P, smem);
}
__global__ __launch_bounds__(256) void k_qk_vct(
    const unsigned short* __restrict__ P,
    unsigned short* __restrict__ term1, unsigned short* __restrict__ sig,
    unsigned short* __restrict__ vcT){
  __shared__ __align__(16) unsigned char smem[16384];
  phase_qkvct_item(blockIdx.x, threadIdx.x, P, term1, sig, vcT, smem);
}
__global__ __launch_bounds__(256) void k_scores(
    const unsigned short* __restrict__ P, const unsigned short* __restrict__ term1,
    const unsigned short* __restrict__ sig, unsigned short* __restrict__ finb){
  __shared__ __align__(16) unsigned char smem[16384];
  phase_scores_item(blockIdx.x, threadIdx.x, P, term1, sig, finb, smem);
}
__global__ __launch_bounds__(256) void k_pv_soft(
    const unsigned short* __restrict__ finb, const unsigned short* __restrict__ vcT,
    unsigned short* __restrict__ O){
  __shared__ __align__(16) unsigned char smem[33024];
  phase_pvsoft_item(blockIdx.x, threadIdx.x, finb, vcT, O, smem);
}
__global__ __launch_bounds__(256) void k_out(
    const unsigned short* __restrict__ O, const unsigned short* __restrict__ woT,
    float* __restrict__ out){
  __shared__ __align__(16) unsigned char smem[16384];
  phase_out_item(blockIdx.x, threadIdx.x, O, woT, out, smem);
}

extern "C" void kernel_launch(void* const* d_in, const int* in_sizes, int n_in,
                              void* d_out, int out_size, void* d_ws, size_t ws_size,
                              hipStream_t stream){
  const float* x  = (const float*)d_in[0];
  const float* w0 = (const float*)d_in[1];
  const float* w1 = (const float*)d_in[2];
  const float* w2 = (const float*)d_in[3];
  const float* w3 = (const float*)d_in[4];
  const float* w4 = (const float*)d_in[5];
  const float* w5 = (const float*)d_in[6];
  const float* w6 = (const float*)d_in[7];
  float* out = (float*)d_out;
  unsigned short* ws = (unsigned short*)d_ws;

  void* args[] = {(void*)&x, (void*)&w0, (void*)&w1, (void*)&w2, (void*)&w3,
                  (void*)&w4, (void*)&w5, (void*)&w6, (void*)&out, (void*)&ws};
  hipError_t err = hipLaunchCooperativeKernel((const void*)k_all, dim3(GRID),
                                              dim3(256), args, 0, stream);
  if (err != hipSuccess){
    // Fallback: proven 6-kernel sequence (identical math).
    unsigned short* wT    = ws;
    unsigned short* xb    = wT    + (size_t)7  * 262144;
    unsigned short* P     = xb    + (size_t)1048576;
    unsigned short* vcT   = P     + (size_t)96 * 65536;
    unsigned short* term1 = vcT   + (size_t)16 * 65536;
    unsigned short* sig   = term1 + (size_t)16 * 1048576;
    unsigned short* O     = sig   + (size_t)16 * 1048576;
    unsigned short* finb  = O     + (size_t)16 * 65536;
    k_prep<<<1472, 256, 0, stream>>>(x, w0, w1, w2, w3, w4, w5, w6, xb, wT);
    k_proj<<<384, 256, 0, stream>>>(xb, wT, P);
    k_qk_vct<<<1408, 256, 0, stream>>>(P, term1, sig, vcT);
    k_scores<<<576, 256, 0, stream>>>(P, term1, sig, finb);
    k_pv_soft<<<1024, 256, 0, stream>>>(finb, vcT, O);
    k_out<<<1024, 256, 0, stream>>>(O, wT + (size_t)6 * 262144, out);
  }
}

// Round 12
// 171.884 us; speedup vs baseline: 2.9840x; 2.9840x over previous
//
#include <hip/hip_runtime.h>
#include <math.h>

// Problem: b=2, h=8, n=1024, d=64, DIM=512. Inputs/outputs FLOAT32.
// Internal pipeline bf16 MFMA (f32 accumulate). SCALE = 1/8.
// R12 = R11 resubmitted verbatim (R11 hit a harness infra failure, never ran).
// R11 = R8 structure (best: 171.8us) + O stored in [b*1024+n][h*64+d] layout
// so k_out's A reads are contiguous. Coop mega-kernel abandoned (R10: 2.6x
// slower — worst-case VGPR/LDS envelope cut all phases to 2 blocks/CU).

typedef __bf16 bf16x8 __attribute__((ext_vector_type(8)));
typedef float f32x4 __attribute__((ext_vector_type(4)));

#define SCALE 0.125f

// async global->LDS: lane deposits 16B at (wave-uniform base + lane*16)
#define GLL(g, l) __builtin_amdgcn_global_load_lds(                         \
    (const __attribute__((address_space(1))) void*)(g),                     \
    (__attribute__((address_space(3))) void*)(l), 16, 0, 0)

__device__ __forceinline__ unsigned short f2bf(float f){
  unsigned int x = __builtin_bit_cast(unsigned int, f);
  unsigned int r = (x + 0x7fffu + ((x >> 16) & 1u)) >> 16;  // RNE
  return (unsigned short)r;
}
__device__ __forceinline__ float bf2f(unsigned short u){
  unsigned int x = ((unsigned int)u) << 16;
  return __builtin_bit_cast(float, x);
}
__device__ __forceinline__ f32x4 mfma16(bf16x8 a, bf16x8 b, f32x4 c){
  return __builtin_amdgcn_mfma_f32_16x16x32_bf16(a, b, c, 0, 0, 0);
}
__device__ __forceinline__ bf16x8 ld8(const unsigned short* p){
  return *(const bf16x8*)p;
}

// ---------------- K0: x f32->bf16 (blocks 0..1023) + weight transpose -------
__global__ __launch_bounds__(256) void k_prep(
    const float* __restrict__ x,
    const float* __restrict__ w0, const float* __restrict__ w1,
    const float* __restrict__ w2, const float* __restrict__ w3,
    const float* __restrict__ w4, const float* __restrict__ w5,
    const float* __restrict__ w6,
    unsigned short* __restrict__ xb, unsigned short* __restrict__ wT){
  int t = threadIdx.x;
  if (blockIdx.x < 1024){
    int i = blockIdx.x * 256 + t;
    float4 v = ((const float4*)x)[i];
    ushort4 o; o.x = f2bf(v.x); o.y = f2bf(v.y); o.z = f2bf(v.z); o.w = f2bf(v.w);
    ((ushort4*)xb)[i] = o;
    return;
  }
  __shared__ float lds[64 * 65];
  int bx = blockIdx.x - 1024;                   // 448 = 7 mats * 64 tiles
  int mat = bx >> 6, tile = bx & 63, tr = tile >> 3, tc = tile & 7;
  int k0 = tr * 64, c0 = tc * 64;
  const float* src;
  switch (mat){
    case 0: src = w0; break; case 1: src = w1; break; case 2: src = w2; break;
    case 3: src = w3; break; case 4: src = w4; break; case 5: src = w5; break;
    default: src = w6; break;
  }
#pragma unroll
  for (int i = 0; i < 4; ++i){
    int r = (t >> 4) + i * 16, c4 = (t & 15) * 4;
    float4 v = *(const float4*)(src + (size_t)(k0 + r) * 512 + c0 + c4);
    lds[r * 65 + c4 + 0] = v.x; lds[r * 65 + c4 + 1] = v.y;
    lds[r * 65 + c4 + 2] = v.z; lds[r * 65 + c4 + 3] = v.w;
  }
  __syncthreads();
  unsigned short* dst = wT + (size_t)mat * 262144;
#pragma unroll
  for (int i = 0; i < 4; ++i){
    int oc = (t >> 4) + i * 16;
    int kq = (t & 15) * 4;
    ushort4 o;
    o.x = f2bf(lds[(kq + 0) * 65 + oc]);
    o.y = f2bf(lds[(kq + 1) * 65 + oc]);
    o.z = f2bf(lds[(kq + 2) * 65 + oc]);
    o.w = f2bf(lds[(kq + 3) * 65 + oc]);
    *(ushort4*)(dst + (size_t)(c0 + oc) * 512 + k0 + kq) = o;
  }
}

// ---------------- K1: fused projections: [2048,512] @ [512,3072] ------------
__global__ __launch_bounds__(256) void k_proj(
    const unsigned short* __restrict__ xb, const unsigned short* __restrict__ wT,
    unsigned short* __restrict__ P){
  __shared__ unsigned short sA[128 * 32], sB[128 * 32];
  int t = threadIdx.x, lane = t & 63, l16 = lane & 15, quad = lane >> 4;
  int w = t >> 6, wm = w >> 1, wn = w & 1;
  int bx = blockIdx.x;                       // 384 = 16 Mtiles * 24 Ntiles
  int mt = bx / 24, nt = bx - mt * 24;
  int M0 = mt * 128, N0 = nt * 128;
  int matb = N0 >> 9;
  int nin = N0 & 511;
  int srow = (lane >> 2), scol = (lane & 3) * 8;
  const unsigned short* gA = xb + (size_t)(M0 + w*32 + srow) * 512 + scol;
  const unsigned short* gB = wT + (size_t)matb * 262144
                               + (size_t)(nin + w*32 + srow) * 512 + scol;
  unsigned short* lA = sA + (w*32) * 32;
  unsigned short* lB = sB + (w*32) * 32;
  f32x4 acc[4][4] = {};
  for (int k0 = 0; k0 < 512; k0 += 32){
    GLL(gA + k0,            lA);
    GLL(gA + k0 + 16*512,   lA + 16*32);
    GLL(gB + k0,            lB);
    GLL(gB + k0 + 16*512,   lB + 16*32);
    __syncthreads();
    bf16x8 aw[4], ax[4];
#pragma unroll
    for (int fi = 0; fi < 4; ++fi)
      aw[fi] = *(const bf16x8*)(sB + (wn*64 + fi*16 + l16) * 32 + quad * 8);
#pragma unroll
    for (int mi = 0; mi < 4; ++mi)
      ax[mi] = *(const bf16x8*)(sA + (wm*64 + mi*16 + l16) * 32 + quad * 8);
#pragma unroll
    for (int fi = 0; fi < 4; ++fi)
#pragma unroll
      for (int mi = 0; mi < 4; ++mi)
        acc[fi][mi] = mfma16(aw[fi], ax[mi], acc[fi][mi]);
    __syncthreads();
  }
#pragma unroll
  for (int fi = 0; fi < 4; ++fi)
#pragma unroll
    for (int mi = 0; mi < 4; ++mi){
      int row = M0 + wm*64 + mi*16 + l16;
      int b_ = row >> 10, n_ = row & 1023;
      int c0 = N0 + wn*64 + fi*16 + quad*4;
      int h = (c0 & 511) >> 6, d = c0 & 63;
      int bh = b_*8 + h;
      ushort4 o;
      o.x = f2bf(acc[fi][mi][0]); o.y = f2bf(acc[fi][mi][1]);
      o.z = f2bf(acc[fi][mi][2]); o.w = f2bf(acc[fi][mi][3]);
      *(ushort4*)(P + (size_t)(matb*16 + bh) * 65536 + (size_t)n_ * 64 + d) = o;
    }
}

// ---------------- K2: vct (blocks 0..255) + qk as 128x128 GLL-staged tiles --
__global__ __launch_bounds__(256) void k_qk_vct(
    const unsigned short* __restrict__ P,
    unsigned short* __restrict__ term1, unsigned short* __restrict__ sig,
    unsigned short* __restrict__ vcT){
  int t = threadIdx.x;
  if (blockIdx.x < 256){
    __shared__ unsigned short lds[64 * 72];
    int bh = blockIdx.x >> 4, nt = blockIdx.x & 15;
    int N0 = nt * 64;
    const unsigned short* src = P + (size_t)(5*16 + bh) * 65536 + (size_t)N0 * 64;
#pragma unroll
    for (int i2 = 0; i2 < 2; ++i2){
      int id = i2 * 256 + t;
      int r = id >> 3, c8 = (id & 7) * 8;
      ushort4 v0 = *(const ushort4*)(src + r * 64 + c8);
      ushort4 v1 = *(const ushort4*)(src + r * 64 + c8 + 4);
      *(ushort4*)(lds + r * 72 + c8) = v0;
      *(ushort4*)(lds + r * 72 + c8 + 4) = v1;
    }
    __syncthreads();
    unsigned short* dst = vcT + (size_t)bh * 65536;
#pragma unroll
    for (int i2 = 0; i2 < 2; ++i2){
      int id = i2 * 256 + t;
      int dd = id >> 3, n8 = (id & 7) * 8;
      ushort4 a, b;
      a.x = lds[(n8+0)*72 + dd]; a.y = lds[(n8+1)*72 + dd];
      a.z = lds[(n8+2)*72 + dd]; a.w = lds[(n8+3)*72 + dd];
      b.x = lds[(n8+4)*72 + dd]; b.y = lds[(n8+5)*72 + dd];
      b.z = lds[(n8+6)*72 + dd]; b.w = lds[(n8+7)*72 + dd];
      *(ushort4*)(dst + (size_t)dd * 1024 + N0 + n8) = a;
      *(ushort4*)(dst + (size_t)dd * 1024 + N0 + n8 + 4) = b;
    }
    return;
  }
  __shared__ unsigned short sA[128 * 32], sB[128 * 32];
  int id = blockIdx.x - 256;
  int bh = id & 15, tt = id >> 4;              // tt in [0,72)
  int mat = (tt >= 36);                        // 0=term1, 1=sig
  int tl = mat ? tt - 36 : tt;
  int ti = 0;
  while (tl >= ti + 1){ tl -= ti + 1; ++ti; }
  int tj = tl;
  int R0, C0;
  const unsigned short *Asrc, *Bsrc;
  if (!mat){ R0 = ti * 128; C0 = tj * 128;     // term1 rows=i, cols=j
             Asrc = P + (size_t)(3*16 + bh) * 65536;      // q_c
             Bsrc = P + (size_t)(2*16 + bh) * 65536; }    // v_u
  else     { R0 = tj * 128; C0 = ti * 128;     // sig rows=k, cols=j
             Asrc = P + (size_t)(0*16 + bh) * 65536;      // q_u
             Bsrc = P + (size_t)(1*16 + bh) * 65536; }    // k_u
  int lane = t & 63, l16 = lane & 15, quad = lane >> 4;
  int w = t >> 6, wm = w >> 1, wn = w & 1;
  int srow = lane >> 2, scol = (lane & 3) * 8;
  const unsigned short* gA = Asrc + (size_t)(R0 + w*32 + srow) * 64 + scol;
  const unsigned short* gB = Bsrc + (size_t)(C0 + w*32 + srow) * 64 + scol;
  unsigned short* lA = sA + (w*32) * 32;
  unsigned short* lB = sB + (w*32) * 32;
  f32x4 acc[4][4] = {};
#pragma unroll
  for (int k0 = 0; k0 < 64; k0 += 32){
    GLL(gA + k0,           lA);
    GLL(gA + k0 + 16*64,   lA + 16*32);
    GLL(gB + k0,           lB);
    GLL(gB + k0 + 16*64,   lB + 16*32);
    __syncthreads();
    bf16x8 af[4], bfr[4];
#pragma unroll
    for (int mi = 0; mi < 4; ++mi)
      af[mi] = *(const bf16x8*)(sA + (wm*64 + mi*16 + l16) * 32 + quad * 8);
#pragma unroll
    for (int fi = 0; fi < 4; ++fi)
      bfr[fi] = *(const bf16x8*)(sB + (wn*64 + fi*16 + l16) * 32 + quad * 8);
#pragma unroll
    for (int fi = 0; fi < 4; ++fi)
#pragma unroll
      for (int mi = 0; mi < 4; ++mi)
        acc[fi][mi] = mfma16(bfr[fi], af[mi], acc[fi][mi]);
    __syncthreads();
  }
  unsigned short* out = (mat ? sig : term1) + (size_t)bh * 1048576;
#pragma unroll
  for (int fi = 0; fi < 4; ++fi)
#pragma unroll
    for (int mi = 0; mi < 4; ++mi){
      int row = R0 + wm*64 + mi*16 + l16;
      int c0 = C0 + wn*64 + fi*16 + quad*4;
      ushort4 o;
#pragma unroll
      for (int r = 0; r < 4; ++r){
        int col = c0 + r;
        float v = acc[fi][mi][r] * SCALE;
        unsigned short res;
        if (!mat) res = (col <= row) ? f2bf(v) : (unsigned short)0;
        else      res = (col >  row) ? f2bf(1.f / (1.f + expf(-v))) : (unsigned short)0;
        ((unsigned short*)&o)[r] = res;
      }
      *(ushort4*)(out + (size_t)row * 1024 + c0) = o;
    }
}

// ---------------- K3: finb(bf16) = S_c - silu(S_u), lower tiles only --------
__global__ __launch_bounds__(256) void k_scores(
    const unsigned short* __restrict__ P, const unsigned short* __restrict__ term1,
    const unsigned short* __restrict__ sig, unsigned short* __restrict__ finb){
  __shared__ unsigned short sA[128 * 32], sB[128 * 32];
  int t = threadIdx.x;
  int bh = blockIdx.x & 15, tt = blockIdx.x >> 4;
  int k = 1, T = 0;
  while (tt >= T + k){ T += k; ++k; }
  int delta = 8 - k;
  int tj = tt - T, ti = tj + delta;
  int M0 = ti * 128, N0 = tj * 128;
  size_t sbase = (size_t)bh * 1048576;
  int lane = t & 63, l16 = lane & 15, quad = lane >> 4;
  int w = t >> 6, wm = w >> 1, wn = w & 1;
  int srow = (lane >> 2), scol = (lane & 3) * 8;
  unsigned short* lA = sA + (w*32) * 32;
  unsigned short* lB = sB + (w*32) * 32;
  f32x4 acc_u[4][4] = {};
  f32x4 acc_c[4][4] = {};
  {
    const unsigned short* gA = term1 + sbase + (size_t)(M0 + w*32 + srow) * 1024 + scol;
    const unsigned short* gB = sig   + sbase + (size_t)(N0 + w*32 + srow) * 1024 + scol;
    int steps = (delta + 1) * 4;
    for (int s = 0; s < steps; ++s){
      int j0 = N0 + s * 32;
      GLL(gA + j0,             lA);
      GLL(gA + j0 + 16*1024,   lA + 16*32);
      GLL(gB + j0,             lB);
      GLL(gB + j0 + 16*1024,   lB + 16*32);
      __syncthreads();
      bf16x8 af[4], bfr[4];
#pragma unroll
      for (int mi = 0; mi < 4; ++mi)
        af[mi] = *(const bf16x8*)(sA + (wm*64 + mi*16 + l16) * 32 + quad * 8);
#pragma unroll
      for (int fi = 0; fi < 4; ++fi)
        bfr[fi] = *(const bf16x8*)(sB + (wn*64 + fi*16 + l16) * 32 + quad * 8);
#pragma unroll
      for (int fi = 0; fi < 4; ++fi)
#pragma unroll
        for (int mi = 0; mi < 4; ++mi)
          acc_u[fi][mi] = mfma16(bfr[fi], af[mi], acc_u[fi][mi]);
      __syncthreads();
    }
  }
  {
    const unsigned short* Qc = P + (size_t)(3*16 + bh) * 65536;
    const unsigned short* Kc = P + (size_t)(4*16 + bh) * 65536;
#pragma unroll
    for (int k0 = 0; k0 < 64; k0 += 32){
      bf16x8 af[4], bfr[4];
#pragma unroll
      for (int mi = 0; mi < 4; ++mi)
        af[mi] = ld8(Qc + (size_t)(M0 + wm*64 + mi*16 + l16) * 64 + k0 + quad * 8);
#pragma unroll
      for (int fi = 0; fi < 4; ++fi)
        bfr[fi] = ld8(Kc + (size_t)(N0 + wn*64 + fi*16 + l16) * 64 + k0 + quad * 8);
#pragma unroll
      for (int fi = 0; fi < 4; ++fi)
#pragma unroll
        for (int mi = 0; mi < 4; ++mi)
          acc_c[fi][mi] = mfma16(bfr[fi], af[mi], acc_c[fi][mi]);
    }
  }
  unsigned short* out = finb + sbase;
#pragma unroll
  for (int fi = 0; fi < 4; ++fi)
#pragma unroll
    for (int mi = 0; mi < 4; ++mi){
      int row = M0 + wm*64 + mi*16 + l16;
      int c0 = N0 + wn*64 + fi*16 + quad*4;
      ushort4 o;
#pragma unroll
      for (int r = 0; r < 4; ++r){
        float su = acc_u[fi][mi][r];
        float v = acc_c[fi][mi][r] * SCALE - su / (1.f + expf(-su));
        ((unsigned short*)&o)[r] = f2bf(v);   // col>row masked downstream
      }
      *(ushort4*)(out + (size_t)row * 1024 + c0) = o;
    }
}

// ---------------- K4: fused softmax + PV; O stored [b*1024+n][h*64+d] -------
__global__ __launch_bounds__(256) void k_pv_soft(
    const unsigned short* __restrict__ finb, const unsigned short* __restrict__ vcT,
    unsigned short* __restrict__ O2){
  __shared__ __align__(16) unsigned char smem[16 * 1032 * 2];  // 33 KB
  unsigned short* lp = (unsigned short*)smem;                  // probs [16][1032]
  float* red = (float*)smem;                                   // overlay
  int t = threadIdx.x;
  int bh = blockIdx.x & 15, mt = 63 - (blockIdx.x >> 4);       // heavy first
  int m0 = mt * 16;
  int kceil = ((m0 + 16 + 31) >> 5) << 5;                      // mult of 32
  {
    int rl = t >> 4, sub = t & 15;
    int rloc = m0 + rl;
    const unsigned short* p = finb + (size_t)bh * 1048576 + (size_t)rloc * 1024;
    float v[8][8];
    float m = -INFINITY;
#pragma unroll
    for (int i = 0; i < 8; ++i){
      int c8 = (sub + 16*i) * 8;
      if (c8 < kceil){
        ushort4 u0 = *(const ushort4*)(p + c8);
        ushort4 u1 = *(const ushort4*)(p + c8 + 4);
        float vv[8] = {bf2f(u0.x), bf2f(u0.y), bf2f(u0.z), bf2f(u0.w),
                       bf2f(u1.x), bf2f(u1.y), bf2f(u1.z), bf2f(u1.w)};
#pragma unroll
        for (int e = 0; e < 8; ++e){
          v[i][e] = (c8 + e <= rloc) ? vv[e] : -INFINITY;
          m = fmaxf(m, v[i][e]);
        }
      }
    }
#pragma unroll
    for (int off = 1; off < 16; off <<= 1) m = fmaxf(m, __shfl_xor(m, off));
    float s = 0.f;
#pragma unroll
    for (int i = 0; i < 8; ++i){
      int c8 = (sub + 16*i) * 8;
      if (c8 < kceil){
#pragma unroll
        for (int e = 0; e < 8; ++e){
          v[i][e] = expf(v[i][e] - m);
          s += v[i][e];
        }
      }
    }
#pragma unroll
    for (int off = 1; off < 16; off <<= 1) s += __shfl_xor(s, off);
    float inv = 1.f / s;
#pragma unroll
    for (int i = 0; i < 8; ++i){
      int c8 = (sub + 16*i) * 8;
      if (c8 < kceil){
        ushort4 o0, o1;
        o0.x = f2bf(v[i][0] * inv); o0.y = f2bf(v[i][1] * inv);
        o0.z = f2bf(v[i][2] * inv); o0.w = f2bf(v[i][3] * inv);
        o1.x = f2bf(v[i][4] * inv); o1.y = f2bf(v[i][5] * inv);
        o1.z = f2bf(v[i][6] * inv); o1.w = f2bf(v[i][7] * inv);
        *(ushort4*)(lp + rl * 1032 + c8) = o0;
        *(ushort4*)(lp + rl * 1032 + c8 + 4) = o1;
      }
    }
  }
  __syncthreads();
  int lane = t & 63, l16 = lane & 15, quad = lane >> 4, w = t >> 6;
  const unsigned short* Bt = vcT + (size_t)bh * 65536;
  int ktot = kceil >> 5;
  int per = (ktot + 3) >> 2;
  int s0 = w * per, s1 = min(s0 + per, ktot);
  f32x4 acc[4] = {};
  for (int s = s0; s < s1; ++s){
    int k0 = s * 32;
    bf16x8 a = *(const bf16x8*)(lp + l16 * 1032 + k0 + quad * 8);
#pragma unroll
    for (int fi = 0; fi < 4; ++fi){
      bf16x8 b = ld8(Bt + (size_t)(fi*16 + l16) * 1024 + k0 + quad * 8);
      acc[fi] = mfma16(a, b, acc[fi]);
    }
  }
  __syncthreads();
#pragma unroll
  for (int fi = 0; fi < 4; ++fi)
#pragma unroll
    for (int r = 0; r < 4; ++r)
      red[w * 1024 + (quad*4 + r) * 64 + fi*16 + l16] = acc[fi][r];
  __syncthreads();
  float4 a0 = ((const float4*)(red + 0*1024))[t];
  float4 a1 = ((const float4*)(red + 1*1024))[t];
  float4 a2 = ((const float4*)(red + 2*1024))[t];
  float4 a3 = ((const float4*)(red + 3*1024))[t];
  ushort4 o;
  o.x = f2bf(a0.x + a1.x + a2.x + a3.x);
  o.y = f2bf(a0.y + a1.y + a2.y + a3.y);
  o.z = f2bf(a0.z + a1.z + a2.z + a3.z);
  o.w = f2bf(a0.w + a1.w + a2.w + a3.w);
  int e = t * 4, row = e >> 6, col = e & 63;
  int b_ = bh >> 3, h_ = bh & 7;
  *(ushort4*)(O2 + (size_t)(b_*1024 + m0 + row) * 512 + h_*64 + col) = o;
}

// ---------------- K5: out(f32) = O_cat @ w_out (contiguous A reads) ---------
__global__ __launch_bounds__(256) void k_out(
    const unsigned short* __restrict__ O2, const unsigned short* __restrict__ woT,
    float* __restrict__ out){
  __shared__ float red[4][1024];
  int t = threadIdx.x, lane = t & 63, l16 = lane & 15, quad = lane >> 4, w = t >> 6;
  int mt = blockIdx.x >> 3, nt = blockIdx.x & 7;
  int m0 = mt * 16, n0 = nt * 64;
  int r_ = m0 + l16;
  f32x4 acc[4] = {};
#pragma unroll
  for (int s = 0; s < 4; ++s){
    int kk = w * 128 + s * 32 + quad * 8;
    bf16x8 a = ld8(O2 + (size_t)r_ * 512 + kk);
#pragma unroll
    for (int fi = 0; fi < 4; ++fi){
      bf16x8 b = ld8(woT + (size_t)(n0 + fi*16 + l16) * 512 + kk);
      acc[fi] = mfma16(a, b, acc[fi]);
    }
  }
#pragma unroll
  for (int fi = 0; fi < 4; ++fi)
#pragma unroll
    for (int r = 0; r < 4; ++r)
      red[w][(quad*4 + r) * 64 + fi*16 + l16] = acc[fi][r];
  __syncthreads();
  float4 a0 = ((const float4*)red[0])[t];
  float4 a1 = ((const float4*)red[1])[t];
  float4 a2 = ((const float4*)red[2])[t];
  float4 a3 = ((const float4*)red[3])[t];
  float4 o;
  o.x = a0.x + a1.x + a2.x + a3.x;
  o.y = a0.y + a1.y + a2.y + a3.y;
  o.z = a0.z + a1.z + a2.z + a3.z;
  o.w = a0.w + a1.w + a2.w + a3.w;
  int e = t * 4, row = e >> 6, col = e & 63;
  *(float4*)(out + (size_t)(m0 + row) * 512 + n0 + col) = o;
}

extern "C" void kernel_launch(void* const* d_in, const int* in_sizes, int n_in,
                              void* d_out, int out_size, void* d_ws, size_t ws_size,
                              hipStream_t stream){
  const float* x = (const float*)d_in[0];
  float* out = (float*)d_out;
  unsigned short* ws = (unsigned short*)d_ws;

  unsigned short* wT    = ws;                                   // 7*262144
  unsigned short* xb    = wT    + (size_t)7  * 262144;          // 1048576
  unsigned short* P     = xb    + (size_t)1048576;              // 96*65536
  unsigned short* vcT   = P     + (size_t)96 * 65536;           // 16*65536
  unsigned short* term1 = vcT   + (size_t)16 * 65536;           // 16*1048576
  unsigned short* sig   = term1 + (size_t)16 * 1048576;         // 16*1048576
  unsigned short* O2    = sig   + (size_t)16 * 1048576;         // 16*65536 ([2048][512])
  unsigned short* finb  = O2    + (size_t)16 * 65536;           // 16*1048576 bf16

  k_prep<<<1472, 256, 0, stream>>>(
      x,
      (const float*)d_in[1], (const float*)d_in[2], (const float*)d_in[3],
      (const float*)d_in[4], (const float*)d_in[5], (const float*)d_in[6],
      (const float*)d_in[7], xb, wT);
  k_proj<<<384, 256, 0, stream>>>(xb, wT, P);
  k_qk_vct<<<1408, 256, 0, stream>>>(P, term1, sig, vcT);
  k_scores<<<576, 256, 0, stream>>>(P, term1, sig, finb);
  k_pv_soft<<<1024, 256, 0, stream>>>(finb, vcT, O2);
  k_out<<<1024, 256, 0, stream>>>(O2, wT + (size_t)6 * 262144, out);
}

// Round 13
// 169.592 us; speedup vs baseline: 3.0243x; 1.0135x over previous
//
#include <hip/hip_runtime.h>
#include <math.h>

// Problem: b=2, h=8, n=1024, d=64, DIM=512. Inputs/outputs FLOAT32.
// Internal pipeline bf16 MFMA (f32 accumulate). SCALE = 1/8.
// R13 = R12 + load-balanced block->tile maps for the triangular kernels:
//  - k_scores: 36-tile permutation, CU-group step-sums 20..36 (was 16..48)
//  - k_pv_soft: snake mt map, CU-group work sums exactly 126 (was 96..156)
// Rationale: blocks i and i+256 land on the same CU (XCD round-robin), so
// monotone work layouts pile heavy tiles onto the same CUs.

typedef __bf16 bf16x8 __attribute__((ext_vector_type(8)));
typedef float f32x4 __attribute__((ext_vector_type(4)));

#define SCALE 0.125f

// async global->LDS: lane deposits 16B at (wave-uniform base + lane*16)
#define GLL(g, l) __builtin_amdgcn_global_load_lds(                         \
    (const __attribute__((address_space(1))) void*)(g),                     \
    (__attribute__((address_space(3))) void*)(l), 16, 0, 0)

__device__ __forceinline__ unsigned short f2bf(float f){
  unsigned int x = __builtin_bit_cast(unsigned int, f);
  unsigned int r = (x + 0x7fffu + ((x >> 16) & 1u)) >> 16;  // RNE
  return (unsigned short)r;
}
__device__ __forceinline__ float bf2f(unsigned short u){
  unsigned int x = ((unsigned int)u) << 16;
  return __builtin_bit_cast(float, x);
}
__device__ __forceinline__ f32x4 mfma16(bf16x8 a, bf16x8 b, f32x4 c){
  return __builtin_amdgcn_mfma_f32_16x16x32_bf16(a, b, c, 0, 0, 0);
}
__device__ __forceinline__ bf16x8 ld8(const unsigned short* p){
  return *(const bf16x8*)p;
}

// balanced tile permutation for k_scores: tt slot -> (ti,tj), ti>=tj.
// CU-group g=tt%16 gets slots {g, g+16, g+32(<36)}; step-sums 20..36.
__device__ const unsigned char SC_TI[36] =
  {2,3,1,3, 7,6,7,5, 6,7,4,5, 6,7,5,7,
   0,2,2,4, 6,7,5,6, 7,4,5,6, 3,4,6,7,
   1,3,4,5};
__device__ const unsigned char SC_TJ[36] =
  {0,1,0,2, 0,0,1,0, 1,2,0,1, 2,3,2,4,
   0,2,1,3, 6,7,4,5, 6,2,3,4, 0,1,3,5,
   1,3,4,5};

// ---------------- K0: x f32->bf16 (blocks 0..1023) + weight transpose -------
__global__ __launch_bounds__(256) void k_prep(
    const float* __restrict__ x,
    const float* __restrict__ w0, const float* __restrict__ w1,
    const float* __restrict__ w2, const float* __restrict__ w3,
    const float* __restrict__ w4, const float* __restrict__ w5,
    const float* __restrict__ w6,
    unsigned short* __restrict__ xb, unsigned short* __restrict__ wT){
  int t = threadIdx.x;
  if (blockIdx.x < 1024){
    int i = blockIdx.x * 256 + t;
    float4 v = ((const float4*)x)[i];
    ushort4 o; o.x = f2bf(v.x); o.y = f2bf(v.y); o.z = f2bf(v.z); o.w = f2bf(v.w);
    ((ushort4*)xb)[i] = o;
    return;
  }
  __shared__ float lds[64 * 65];
  int bx = blockIdx.x - 1024;                   // 448 = 7 mats * 64 tiles
  int mat = bx >> 6, tile = bx & 63, tr = tile >> 3, tc = tile & 7;
  int k0 = tr * 64, c0 = tc * 64;
  const float* src;
  switch (mat){
    case 0: src = w0; break; case 1: src = w1; break; case 2: src = w2; break;
    case 3: src = w3; break; case 4: src = w4; break; case 5: src = w5; break;
    default: src = w6; break;
  }
#pragma unroll
  for (int i = 0; i < 4; ++i){
    int r = (t >> 4) + i * 16, c4 = (t & 15) * 4;
    float4 v = *(const float4*)(src + (size_t)(k0 + r) * 512 + c0 + c4);
    lds[r * 65 + c4 + 0] = v.x; lds[r * 65 + c4 + 1] = v.y;
    lds[r * 65 + c4 + 2] = v.z; lds[r * 65 + c4 + 3] = v.w;
  }
  __syncthreads();
  unsigned short* dst = wT + (size_t)mat * 262144;
#pragma unroll
  for (int i = 0; i < 4; ++i){
    int oc = (t >> 4) + i * 16;
    int kq = (t & 15) * 4;
    ushort4 o;
    o.x = f2bf(lds[(kq + 0) * 65 + oc]);
    o.y = f2bf(lds[(kq + 1) * 65 + oc]);
    o.z = f2bf(lds[(kq + 2) * 65 + oc]);
    o.w = f2bf(lds[(kq + 3) * 65 + oc]);
    *(ushort4*)(dst + (size_t)(c0 + oc) * 512 + k0 + kq) = o;
  }
}

// ---------------- K1: fused projections: [2048,512] @ [512,3072] ------------
__global__ __launch_bounds__(256) void k_proj(
    const unsigned short* __restrict__ xb, const unsigned short* __restrict__ wT,
    unsigned short* __restrict__ P){
  __shared__ unsigned short sA[128 * 32], sB[128 * 32];
  int t = threadIdx.x, lane = t & 63, l16 = lane & 15, quad = lane >> 4;
  int w = t >> 6, wm = w >> 1, wn = w & 1;
  int bx = blockIdx.x;                       // 384 = 16 Mtiles * 24 Ntiles
  int mt = bx / 24, nt = bx - mt * 24;
  int M0 = mt * 128, N0 = nt * 128;
  int matb = N0 >> 9;
  int nin = N0 & 511;
  int srow = (lane >> 2), scol = (lane & 3) * 8;
  const unsigned short* gA = xb + (size_t)(M0 + w*32 + srow) * 512 + scol;
  const unsigned short* gB = wT + (size_t)matb * 262144
                               + (size_t)(nin + w*32 + srow) * 512 + scol;
  unsigned short* lA = sA + (w*32) * 32;
  unsigned short* lB = sB + (w*32) * 32;
  f32x4 acc[4][4] = {};
  for (int k0 = 0; k0 < 512; k0 += 32){
    GLL(gA + k0,            lA);
    GLL(gA + k0 + 16*512,   lA + 16*32);
    GLL(gB + k0,            lB);
    GLL(gB + k0 + 16*512,   lB + 16*32);
    __syncthreads();
    bf16x8 aw[4], ax[4];
#pragma unroll
    for (int fi = 0; fi < 4; ++fi)
      aw[fi] = *(const bf16x8*)(sB + (wn*64 + fi*16 + l16) * 32 + quad * 8);
#pragma unroll
    for (int mi = 0; mi < 4; ++mi)
      ax[mi] = *(const bf16x8*)(sA + (wm*64 + mi*16 + l16) * 32 + quad * 8);
#pragma unroll
    for (int fi = 0; fi < 4; ++fi)
#pragma unroll
      for (int mi = 0; mi < 4; ++mi)
        acc[fi][mi] = mfma16(aw[fi], ax[mi], acc[fi][mi]);
    __syncthreads();
  }
#pragma unroll
  for (int fi = 0; fi < 4; ++fi)
#pragma unroll
    for (int mi = 0; mi < 4; ++mi){
      int row = M0 + wm*64 + mi*16 + l16;
      int b_ = row >> 10, n_ = row & 1023;
      int c0 = N0 + wn*64 + fi*16 + quad*4;
      int h = (c0 & 511) >> 6, d = c0 & 63;
      int bh = b_*8 + h;
      ushort4 o;
      o.x = f2bf(acc[fi][mi][0]); o.y = f2bf(acc[fi][mi][1]);
      o.z = f2bf(acc[fi][mi][2]); o.w = f2bf(acc[fi][mi][3]);
      *(ushort4*)(P + (size_t)(matb*16 + bh) * 65536 + (size_t)n_ * 64 + d) = o;
    }
}

// ---------------- K2: vct (blocks 0..255) + qk as 128x128 GLL-staged tiles --
__global__ __launch_bounds__(256) void k_qk_vct(
    const unsigned short* __restrict__ P,
    unsigned short* __restrict__ term1, unsigned short* __restrict__ sig,
    unsigned short* __restrict__ vcT){
  int t = threadIdx.x;
  if (blockIdx.x < 256){
    __shared__ unsigned short lds[64 * 72];
    int bh = blockIdx.x >> 4, nt = blockIdx.x & 15;
    int N0 = nt * 64;
    const unsigned short* src = P + (size_t)(5*16 + bh) * 65536 + (size_t)N0 * 64;
#pragma unroll
    for (int i2 = 0; i2 < 2; ++i2){
      int id = i2 * 256 + t;
      int r = id >> 3, c8 = (id & 7) * 8;
      ushort4 v0 = *(const ushort4*)(src + r * 64 + c8);
      ushort4 v1 = *(const ushort4*)(src + r * 64 + c8 + 4);
      *(ushort4*)(lds + r * 72 + c8) = v0;
      *(ushort4*)(lds + r * 72 + c8 + 4) = v1;
    }
    __syncthreads();
    unsigned short* dst = vcT + (size_t)bh * 65536;
#pragma unroll
    for (int i2 = 0; i2 < 2; ++i2){
      int id = i2 * 256 + t;
      int dd = id >> 3, n8 = (id & 7) * 8;
      ushort4 a, b;
      a.x = lds[(n8+0)*72 + dd]; a.y = lds[(n8+1)*72 + dd];
      a.z = lds[(n8+2)*72 + dd]; a.w = lds[(n8+3)*72 + dd];
      b.x = lds[(n8+4)*72 + dd]; b.y = lds[(n8+5)*72 + dd];
      b.z = lds[(n8+6)*72 + dd]; b.w = lds[(n8+7)*72 + dd];
      *(ushort4*)(dst + (size_t)dd * 1024 + N0 + n8) = a;
      *(ushort4*)(dst + (size_t)dd * 1024 + N0 + n8 + 4) = b;
    }
    return;
  }
  __shared__ unsigned short sA[128 * 32], sB[128 * 32];
  int id = blockIdx.x - 256;
  int bh = id & 15, tt = id >> 4;              // tt in [0,72)
  int mat = (tt >= 36);                        // 0=term1, 1=sig
  int tl = mat ? tt - 36 : tt;
  int ti = 0;
  while (tl >= ti + 1){ tl -= ti + 1; ++ti; }
  int tj = tl;
  int R0, C0;
  const unsigned short *Asrc, *Bsrc;
  if (!mat){ R0 = ti * 128; C0 = tj * 128;     // term1 rows=i, cols=j
             Asrc = P + (size_t)(3*16 + bh) * 65536;      // q_c
             Bsrc = P + (size_t)(2*16 + bh) * 65536; }    // v_u
  else     { R0 = tj * 128; C0 = ti * 128;     // sig rows=k, cols=j
             Asrc = P + (size_t)(0*16 + bh) * 65536;      // q_u
             Bsrc = P + (size_t)(1*16 + bh) * 65536; }    // k_u
  int lane = t & 63, l16 = lane & 15, quad = lane >> 4;
  int w = t >> 6, wm = w >> 1, wn = w & 1;
  int srow = lane >> 2, scol = (lane & 3) * 8;
  const unsigned short* gA = Asrc + (size_t)(R0 + w*32 + srow) * 64 + scol;
  const unsigned short* gB = Bsrc + (size_t)(C0 + w*32 + srow) * 64 + scol;
  unsigned short* lA = sA + (w*32) * 32;
  unsigned short* lB = sB + (w*32) * 32;
  f32x4 acc[4][4] = {};
#pragma unroll
  for (int k0 = 0; k0 < 64; k0 += 32){
    GLL(gA + k0,           lA);
    GLL(gA + k0 + 16*64,   lA + 16*32);
    GLL(gB + k0,           lB);
    GLL(gB + k0 + 16*64,   lB + 16*32);
    __syncthreads();
    bf16x8 af[4], bfr[4];
#pragma unroll
    for (int mi = 0; mi < 4; ++mi)
      af[mi] = *(const bf16x8*)(sA + (wm*64 + mi*16 + l16) * 32 + quad * 8);
#pragma unroll
    for (int fi = 0; fi < 4; ++fi)
      bfr[fi] = *(const bf16x8*)(sB + (wn*64 + fi*16 + l16) * 32 + quad * 8);
#pragma unroll
    for (int fi = 0; fi < 4; ++fi)
#pragma unroll
      for (int mi = 0; mi < 4; ++mi)
        acc[fi][mi] = mfma16(bfr[fi], af[mi], acc[fi][mi]);
    __syncthreads();
  }
  unsigned short* out = (mat ? sig : term1) + (size_t)bh * 1048576;
#pragma unroll
  for (int fi = 0; fi < 4; ++fi)
#pragma unroll
    for (int mi = 0; mi < 4; ++mi){
      int row = R0 + wm*64 + mi*16 + l16;
      int c0 = C0 + wn*64 + fi*16 + quad*4;
      ushort4 o;
#pragma unroll
      for (int r = 0; r < 4; ++r){
        int col = c0 + r;
        float v = acc[fi][mi][r] * SCALE;
        unsigned short res;
        if (!mat) res = (col <= row) ? f2bf(v) : (unsigned short)0;
        else      res = (col >  row) ? f2bf(1.f / (1.f + expf(-v))) : (unsigned short)0;
        ((unsigned short*)&o)[r] = res;
      }
      *(ushort4*)(out + (size_t)row * 1024 + c0) = o;
    }
}

// ---------------- K3: finb(bf16) = S_c - silu(S_u), lower tiles only --------
// Balanced tile permutation via SC_TI/SC_TJ (see top).
__global__ __launch_bounds__(256) void k_scores(
    const unsigned short* __restrict__ P, const unsigned short* __restrict__ term1,
    const unsigned short* __restrict__ sig, unsigned short* __restrict__ finb){
  __shared__ unsigned short sA[128 * 32], sB[128 * 32];
  int t = threadIdx.x;
  int bh = blockIdx.x & 15, tt = blockIdx.x >> 4;
  int ti = SC_TI[tt], tj = SC_TJ[tt];
  int delta = ti - tj;
  int M0 = ti * 128, N0 = tj * 128;
  size_t sbase = (size_t)bh * 1048576;
  int lane = t & 63, l16 = lane & 15, quad = lane >> 4;
  int w = t >> 6, wm = w >> 1, wn = w & 1;
  int srow = (lane >> 2), scol = (lane & 3) * 8;
  unsigned short* lA = sA + (w*32) * 32;
  unsigned short* lB = sB + (w*32) * 32;
  f32x4 acc_u[4][4] = {};
  f32x4 acc_c[4][4] = {};
  {
    const unsigned short* gA = term1 + sbase + (size_t)(M0 + w*32 + srow) * 1024 + scol;
    const unsigned short* gB = sig   + sbase + (size_t)(N0 + w*32 + srow) * 1024 + scol;
    int steps = (delta + 1) * 4;
    for (int s = 0; s < steps; ++s){
      int j0 = N0 + s * 32;
      GLL(gA + j0,             lA);
      GLL(gA + j0 + 16*1024,   lA + 16*32);
      GLL(gB + j0,             lB);
      GLL(gB + j0 + 16*1024,   lB + 16*32);
      __syncthreads();
      bf16x8 af[4], bfr[4];
#pragma unroll
      for (int mi = 0; mi < 4; ++mi)
        af[mi] = *(const bf16x8*)(sA + (wm*64 + mi*16 + l16) * 32 + quad * 8);
#pragma unroll
      for (int fi = 0; fi < 4; ++fi)
        bfr[fi] = *(const bf16x8*)(sB + (wn*64 + fi*16 + l16) * 32 + quad * 8);
#pragma unroll
      for (int fi = 0; fi < 4; ++fi)
#pragma unroll
        for (int mi = 0; mi < 4; ++mi)
          acc_u[fi][mi] = mfma16(bfr[fi], af[mi], acc_u[fi][mi]);
      __syncthreads();
    }
  }
  {
    const unsigned short* Qc = P + (size_t)(3*16 + bh) * 65536;
    const unsigned short* Kc = P + (size_t)(4*16 + bh) * 65536;
#pragma unroll
    for (int k0 = 0; k0 < 64; k0 += 32){
      bf16x8 af[4], bfr[4];
#pragma unroll
      for (int mi = 0; mi < 4; ++mi)
        af[mi] = ld8(Qc + (size_t)(M0 + wm*64 + mi*16 + l16) * 64 + k0 + quad * 8);
#pragma unroll
      for (int fi = 0; fi < 4; ++fi)
        bfr[fi] = ld8(Kc + (size_t)(N0 + wn*64 + fi*16 + l16) * 64 + k0 + quad * 8);
#pragma unroll
      for (int fi = 0; fi < 4; ++fi)
#pragma unroll
        for (int mi = 0; mi < 4; ++mi)
          acc_c[fi][mi] = mfma16(bfr[fi], af[mi], acc_c[fi][mi]);
    }
  }
  unsigned short* out = finb + sbase;
#pragma unroll
  for (int fi = 0; fi < 4; ++fi)
#pragma unroll
    for (int mi = 0; mi < 4; ++mi){
      int row = M0 + wm*64 + mi*16 + l16;
      int c0 = N0 + wn*64 + fi*16 + quad*4;
      ushort4 o;
#pragma unroll
      for (int r = 0; r < 4; ++r){
        float su = acc_u[fi][mi][r];
        float v = acc_c[fi][mi][r] * SCALE - su / (1.f + expf(-su));
        ((unsigned short*)&o)[r] = f2bf(v);   // col>row masked downstream
      }
      *(ushort4*)(out + (size_t)row * 1024 + c0) = o;
    }
}

// ---------------- K4: fused softmax + PV; snake mt map; O2 [2048][512] ------
__global__ __launch_bounds__(256) void k_pv_soft(
    const unsigned short* __restrict__ finb, const unsigned short* __restrict__ vcT,
    unsigned short* __restrict__ O2){
  __shared__ __align__(16) unsigned char smem[16 * 1032 * 2];  // 33 KB
  unsigned short* lp = (unsigned short*)smem;                  // probs [16][1032]
  float* red = (float*)smem;                                   // overlay
  int t = threadIdx.x;
  int bh = blockIdx.x & 15;
  int r4 = blockIdx.x >> 8, g = (blockIdx.x >> 4) & 15;
  // snake: CU-group g gets mts {63-g, 32+g, 31-g, g} -> work-sum 126 const
  int mt = (r4 == 0) ? 63 - g : (r4 == 1) ? 32 + g : (r4 == 2) ? 31 - g : g;
  int m0 = mt * 16;
  int kceil = ((m0 + 16 + 31) >> 5) << 5;                      // mult of 32
  {
    int rl = t >> 4, sub = t & 15;
    int rloc = m0 + rl;
    const unsigned short* p = finb + (size_t)bh * 1048576 + (size_t)rloc * 1024;
    float v[8][8];
    float m = -INFINITY;
#pragma unroll
    for (int i = 0; i < 8; ++i){
      int c8 = (sub + 16*i) * 8;
      if (c8 < kceil){
        ushort4 u0 = *(const ushort4*)(p + c8);
        ushort4 u1 = *(const ushort4*)(p + c8 + 4);
        float vv[8] = {bf2f(u0.x), bf2f(u0.y), bf2f(u0.z), bf2f(u0.w),
                       bf2f(u1.x), bf2f(u1.y), bf2f(u1.z), bf2f(u1.w)};
#pragma unroll
        for (int e = 0; e < 8; ++e){
          v[i][e] = (c8 + e <= rloc) ? vv[e] : -INFINITY;
          m = fmaxf(m, v[i][e]);
        }
      }
    }
#pragma unroll
    for (int off = 1; off < 16; off <<= 1) m = fmaxf(m, __shfl_xor(m, off));
    float s = 0.f;
#pragma unroll
    for (int i = 0; i < 8; ++i){
      int c8 = (sub + 16*i) * 8;
      if (c8 < kceil){
#pragma unroll
        for (int e = 0; e < 8; ++e){
          v[i][e] = expf(v[i][e] - m);
          s += v[i][e];
        }
      }
    }
#pragma unroll
    for (int off = 1; off < 16; off <<= 1) s += __shfl_xor(s, off);
    float inv = 1.f / s;
#pragma unroll
    for (int i = 0; i < 8; ++i){
      int c8 = (sub + 16*i) * 8;
      if (c8 < kceil){
        ushort4 o0, o1;
        o0.x = f2bf(v[i][0] * inv); o0.y = f2bf(v[i][1] * inv);
        o0.z = f2bf(v[i][2] * inv); o0.w = f2bf(v[i][3] * inv);
        o1.x = f2bf(v[i][4] * inv); o1.y = f2bf(v[i][5] * inv);
        o1.z = f2bf(v[i][6] * inv); o1.w = f2bf(v[i][7] * inv);
        *(ushort4*)(lp + rl * 1032 + c8) = o0;
        *(ushort4*)(lp + rl * 1032 + c8 + 4) = o1;
      }
    }
  }
  __syncthreads();
  int lane = t & 63, l16 = lane & 15, quad = lane >> 4, w = t >> 6;
  const unsigned short* Bt = vcT + (size_t)bh * 65536;
  int ktot = kceil >> 5;
  int per = (ktot + 3) >> 2;
  int s0 = w * per, s1 = min(s0 + per, ktot);
  f32x4 acc[4] = {};
  for (int s = s0; s < s1; ++s){
    int k0 = s * 32;
    bf16x8 a = *(const bf16x8*)(lp + l16 * 1032 + k0 + quad * 8);
#pragma unroll
    for (int fi = 0; fi < 4; ++fi){
      bf16x8 b = ld8(Bt + (size_t)(fi*16 + l16) * 1024 + k0 + quad * 8);
      acc[fi] = mfma16(a, b, acc[fi]);
    }
  }
  __syncthreads();
#pragma unroll
  for (int fi = 0; fi < 4; ++fi)
#pragma unroll
    for (int r = 0; r < 4; ++r)
      red[w * 1024 + (quad*4 + r) * 64 + fi*16 + l16] = acc[fi][r];
  __syncthreads();
  float4 a0 = ((const float4*)(red + 0*1024))[t];
  float4 a1 = ((const float4*)(red + 1*1024))[t];
  float4 a2 = ((const float4*)(red + 2*1024))[t];
  float4 a3 = ((const float4*)(red + 3*1024))[t];
  ushort4 o;
  o.x = f2bf(a0.x + a1.x + a2.x + a3.x);
  o.y = f2bf(a0.y + a1.y + a2.y + a3.y);
  o.z = f2bf(a0.z + a1.z + a2.z + a3.z);
  o.w = f2bf(a0.w + a1.w + a2.w + a3.w);
  int e = t * 4, row = e >> 6, col = e & 63;
  int b_ = bh >> 3, h_ = bh & 7;
  *(ushort4*)(O2 + (size_t)(b_*1024 + m0 + row) * 512 + h_*64 + col) = o;
}

// ---------------- K5: out(f32) = O_cat @ w_out (contiguous A reads) ---------
__global__ __launch_bounds__(256) void k_out(
    const unsigned short* __restrict__ O2, const unsigned short* __restrict__ woT,
    float* __restrict__ out){
  __shared__ float red[4][1024];
  int t = threadIdx.x, lane = t & 63, l16 = lane & 15, quad = lane >> 4, w = t >> 6;
  int mt = blockIdx.x >> 3, nt = blockIdx.x & 7;
  int m0 = mt * 16, n0 = nt * 64;
  int r_ = m0 + l16;
  f32x4 acc[4] = {};
#pragma unroll
  for (int s = 0; s < 4; ++s){
    int kk = w * 128 + s * 32 + quad * 8;
    bf16x8 a = ld8(O2 + (size_t)r_ * 512 + kk);
#pragma unroll
    for (int fi = 0; fi < 4; ++fi){
      bf16x8 b = ld8(woT + (size_t)(n0 + fi*16 + l16) * 512 + kk);
      acc[fi] = mfma16(a, b, acc[fi]);
    }
  }
#pragma unroll
  for (int fi = 0; fi < 4; ++fi)
#pragma unroll
    for (int r = 0; r < 4; ++r)
      red[w][(quad*4 + r) * 64 + fi*16 + l16] = acc[fi][r];
  __syncthreads();
  float4 a0 = ((const float4*)red[0])[t];
  float4 a1 = ((const float4*)red[1])[t];
  float4 a2 = ((const float4*)red[2])[t];
  float4 a3 = ((const float4*)red[3])[t];
  float4 o;
  o.x = a0.x + a1.x + a2.x + a3.x;
  o.y = a0.y + a1.y + a2.y + a3.y;
  o.z = a0.z + a1.z + a2.z + a3.z;
  o.w = a0.w + a1.w + a2.w + a3.w;
  int e = t * 4, row = e >> 6, col = e & 63;
  *(float4*)(out + (size_t)(m0 + row) * 512 + n0 + col) = o;
}

extern "C" void kernel_launch(void* const* d_in, const int* in_sizes, int n_in,
                              void* d_out, int out_size, void* d_ws, size_t ws_size,
                              hipStream_t stream){
  const float* x = (const float*)d_in[0];
  float* out = (float*)d_out;
  unsigned short* ws = (unsigned short*)d_ws;

  unsigned short* wT    = ws;                                   // 7*262144
  unsigned short* xb    = wT    + (size_t)7  * 262144;          // 1048576
  unsigned short* P     = xb    + (size_t)1048576;              // 96*65536
  unsigned short* vcT   = P     + (size_t)96 * 65536;           // 16*65536
  unsigned short* term1 = vcT   + (size_t)16 * 65536;           // 16*1048576
  unsigned short* sig   = term1 + (size_t)16 * 1048576;         // 16*1048576
  unsigned short* O2    = sig   + (size_t)16 * 1048576;         // 16*65536 ([2048][512])
  unsigned short* finb  = O2    + (size_t)16 * 65536;           // 16*1048576 bf16

  k_prep<<<1472, 256, 0, stream>>>(
      x,
      (const float*)d_in[1], (const float*)d_in[2], (const float*)d_in[3],
      (const float*)d_in[4], (const float*)d_in[5], (const float*)d_in[6],
      (const float*)d_in[7], xb, wT);
  k_proj<<<384, 256, 0, stream>>>(xb, wT, P);
  k_qk_vct<<<1408, 256, 0, stream>>>(P, term1, sig, vcT);
  k_scores<<<576, 256, 0, stream>>>(P, term1, sig, finb);
  k_pv_soft<<<1024, 256, 0, stream>>>(finb, vcT, O2);
  k_out<<<1024, 256, 0, stream>>>(O2, wT + (size_t)6 * 262144, out);
}

// Round 14
// 167.549 us; speedup vs baseline: 3.0612x; 1.0122x over previous
//
#include <hip/hip_runtime.h>
#include <math.h>

// Problem: b=2, h=8, n=1024, d=64, DIM=512. Inputs/outputs FLOAT32.
// Internal pipeline bf16 MFMA (f32 accumulate). SCALE = 1/8.
// R14 = R13 + k_proj retiled 128x128/384blk -> 64x128/768blk (exactly 3/CU;
// 384 = 1.5x256 left half the CUs with a 2x makespan tail).

typedef __bf16 bf16x8 __attribute__((ext_vector_type(8)));
typedef float f32x4 __attribute__((ext_vector_type(4)));

#define SCALE 0.125f

// async global->LDS: lane deposits 16B at (wave-uniform base + lane*16)
#define GLL(g, l) __builtin_amdgcn_global_load_lds(                         \
    (const __attribute__((address_space(1))) void*)(g),                     \
    (__attribute__((address_space(3))) void*)(l), 16, 0, 0)

__device__ __forceinline__ unsigned short f2bf(float f){
  unsigned int x = __builtin_bit_cast(unsigned int, f);
  unsigned int r = (x + 0x7fffu + ((x >> 16) & 1u)) >> 16;  // RNE
  return (unsigned short)r;
}
__device__ __forceinline__ float bf2f(unsigned short u){
  unsigned int x = ((unsigned int)u) << 16;
  return __builtin_bit_cast(float, x);
}
__device__ __forceinline__ f32x4 mfma16(bf16x8 a, bf16x8 b, f32x4 c){
  return __builtin_amdgcn_mfma_f32_16x16x32_bf16(a, b, c, 0, 0, 0);
}
__device__ __forceinline__ bf16x8 ld8(const unsigned short* p){
  return *(const bf16x8*)p;
}

// balanced tile permutation for k_scores (R13, max-slot already optimal at 9)
__device__ const unsigned char SC_TI[36] =
  {2,3,1,3, 7,6,7,5, 6,7,4,5, 6,7,5,7,
   0,2,2,4, 6,7,5,6, 7,4,5,6, 3,4,6,7,
   1,3,4,5};
__device__ const unsigned char SC_TJ[36] =
  {0,1,0,2, 0,0,1,0, 1,2,0,1, 2,3,2,4,
   0,2,1,3, 6,7,4,5, 6,2,3,4, 0,1,3,5,
   1,3,4,5};

// ---------------- K0: x f32->bf16 (blocks 0..1023) + weight transpose -------
__global__ __launch_bounds__(256) void k_prep(
    const float* __restrict__ x,
    const float* __restrict__ w0, const float* __restrict__ w1,
    const float* __restrict__ w2, const float* __restrict__ w3,
    const float* __restrict__ w4, const float* __restrict__ w5,
    const float* __restrict__ w6,
    unsigned short* __restrict__ xb, unsigned short* __restrict__ wT){
  int t = threadIdx.x;
  if (blockIdx.x < 1024){
    int i = blockIdx.x * 256 + t;
    float4 v = ((const float4*)x)[i];
    ushort4 o; o.x = f2bf(v.x); o.y = f2bf(v.y); o.z = f2bf(v.z); o.w = f2bf(v.w);
    ((ushort4*)xb)[i] = o;
    return;
  }
  __shared__ float lds[64 * 65];
  int bx = blockIdx.x - 1024;                   // 448 = 7 mats * 64 tiles
  int mat = bx >> 6, tile = bx & 63, tr = tile >> 3, tc = tile & 7;
  int k0 = tr * 64, c0 = tc * 64;
  const float* src;
  switch (mat){
    case 0: src = w0; break; case 1: src = w1; break; case 2: src = w2; break;
    case 3: src = w3; break; case 4: src = w4; break; case 5: src = w5; break;
    default: src = w6; break;
  }
#pragma unroll
  for (int i = 0; i < 4; ++i){
    int r = (t >> 4) + i * 16, c4 = (t & 15) * 4;
    float4 v = *(const float4*)(src + (size_t)(k0 + r) * 512 + c0 + c4);
    lds[r * 65 + c4 + 0] = v.x; lds[r * 65 + c4 + 1] = v.y;
    lds[r * 65 + c4 + 2] = v.z; lds[r * 65 + c4 + 3] = v.w;
  }
  __syncthreads();
  unsigned short* dst = wT + (size_t)mat * 262144;
#pragma unroll
  for (int i = 0; i < 4; ++i){
    int oc = (t >> 4) + i * 16;
    int kq = (t & 15) * 4;
    ushort4 o;
    o.x = f2bf(lds[(kq + 0) * 65 + oc]);
    o.y = f2bf(lds[(kq + 1) * 65 + oc]);
    o.z = f2bf(lds[(kq + 2) * 65 + oc]);
    o.w = f2bf(lds[(kq + 3) * 65 + oc]);
    *(ushort4*)(dst + (size_t)(c0 + oc) * 512 + k0 + kq) = o;
  }
}

// ---------------- K1: fused projections, 64x128 tiles, 768 blocks -----------
__global__ __launch_bounds__(256) void k_proj(
    const unsigned short* __restrict__ xb, const unsigned short* __restrict__ wT,
    unsigned short* __restrict__ P){
  __shared__ unsigned short sA[64 * 32], sB[128 * 32];
  int t = threadIdx.x, lane = t & 63, l16 = lane & 15, quad = lane >> 4;
  int w = t >> 6, wm = w >> 1, wn = w & 1;
  int bx = blockIdx.x;                       // 768 = 32 Mtiles * 24 Ntiles
  int mt = bx / 24, nt = bx - mt * 24;
  int M0 = mt * 64, N0 = nt * 128;
  int matb = N0 >> 9;
  int nin = N0 & 511;
  int srow = (lane >> 2), scol = (lane & 3) * 8;
  const unsigned short* gA = xb + (size_t)(M0 + w*16 + srow) * 512 + scol;
  const unsigned short* gB = wT + (size_t)matb * 262144
                               + (size_t)(nin + w*32 + srow) * 512 + scol;
  unsigned short* lA = sA + (w*16) * 32;
  unsigned short* lB = sB + (w*32) * 32;
  f32x4 acc[4][2] = {};                      // [fi=wcol grp][mi=xrow grp]
  for (int k0 = 0; k0 < 512; k0 += 32){
    GLL(gA + k0,            lA);
    GLL(gB + k0,            lB);
    GLL(gB + k0 + 16*512,   lB + 16*32);
    __syncthreads();
    bf16x8 aw[4], ax[2];
#pragma unroll
    for (int fi = 0; fi < 4; ++fi)
      aw[fi] = *(const bf16x8*)(sB + (wn*64 + fi*16 + l16) * 32 + quad * 8);
#pragma unroll
    for (int mi = 0; mi < 2; ++mi)
      ax[mi] = *(const bf16x8*)(sA + (wm*32 + mi*16 + l16) * 32 + quad * 8);
#pragma unroll
    for (int fi = 0; fi < 4; ++fi)
#pragma unroll
      for (int mi = 0; mi < 2; ++mi)
        acc[fi][mi] = mfma16(aw[fi], ax[mi], acc[fi][mi]);
    __syncthreads();
  }
#pragma unroll
  for (int fi = 0; fi < 4; ++fi)
#pragma unroll
    for (int mi = 0; mi < 2; ++mi){
      int row = M0 + wm*32 + mi*16 + l16;
      int b_ = row >> 10, n_ = row & 1023;
      int c0 = N0 + wn*64 + fi*16 + quad*4;
      int h = (c0 & 511) >> 6, d = c0 & 63;
      int bh = b_*8 + h;
      ushort4 o;
      o.x = f2bf(acc[fi][mi][0]); o.y = f2bf(acc[fi][mi][1]);
      o.z = f2bf(acc[fi][mi][2]); o.w = f2bf(acc[fi][mi][3]);
      *(ushort4*)(P + (size_t)(matb*16 + bh) * 65536 + (size_t)n_ * 64 + d) = o;
    }
}

// ---------------- K2: vct (blocks 0..255) + qk as 128x128 GLL-staged tiles --
__global__ __launch_bounds__(256) void k_qk_vct(
    const unsigned short* __restrict__ P,
    unsigned short* __restrict__ term1, unsigned short* __restrict__ sig,
    unsigned short* __restrict__ vcT){
  int t = threadIdx.x;
  if (blockIdx.x < 256){
    __shared__ unsigned short lds[64 * 72];
    int bh = blockIdx.x >> 4, nt = blockIdx.x & 15;
    int N0 = nt * 64;
    const unsigned short* src = P + (size_t)(5*16 + bh) * 65536 + (size_t)N0 * 64;
#pragma unroll
    for (int i2 = 0; i2 < 2; ++i2){
      int id = i2 * 256 + t;
      int r = id >> 3, c8 = (id & 7) * 8;
      ushort4 v0 = *(const ushort4*)(src + r * 64 + c8);
      ushort4 v1 = *(const ushort4*)(src + r * 64 + c8 + 4);
      *(ushort4*)(lds + r * 72 + c8) = v0;
      *(ushort4*)(lds + r * 72 + c8 + 4) = v1;
    }
    __syncthreads();
    unsigned short* dst = vcT + (size_t)bh * 65536;
#pragma unroll
    for (int i2 = 0; i2 < 2; ++i2){
      int id = i2 * 256 + t;
      int dd = id >> 3, n8 = (id & 7) * 8;
      ushort4 a, b;
      a.x = lds[(n8+0)*72 + dd]; a.y = lds[(n8+1)*72 + dd];
      a.z = lds[(n8+2)*72 + dd]; a.w = lds[(n8+3)*72 + dd];
      b.x = lds[(n8+4)*72 + dd]; b.y = lds[(n8+5)*72 + dd];
      b.z = lds[(n8+6)*72 + dd]; b.w = lds[(n8+7)*72 + dd];
      *(ushort4*)(dst + (size_t)dd * 1024 + N0 + n8) = a;
      *(ushort4*)(dst + (size_t)dd * 1024 + N0 + n8 + 4) = b;
    }
    return;
  }
  __shared__ unsigned short sA[128 * 32], sB[128 * 32];
  int id = blockIdx.x - 256;
  int bh = id & 15, tt = id >> 4;              // tt in [0,72)
  int mat = (tt >= 36);                        // 0=term1, 1=sig
  int tl = mat ? tt - 36 : tt;
  int ti = 0;
  while (tl >= ti + 1){ tl -= ti + 1; ++ti; }
  int tj = tl;
  int R0, C0;
  const unsigned short *Asrc, *Bsrc;
  if (!mat){ R0 = ti * 128; C0 = tj * 128;     // term1 rows=i, cols=j
             Asrc = P + (size_t)(3*16 + bh) * 65536;      // q_c
             Bsrc = P + (size_t)(2*16 + bh) * 65536; }    // v_u
  else     { R0 = tj * 128; C0 = ti * 128;     // sig rows=k, cols=j
             Asrc = P + (size_t)(0*16 + bh) * 65536;      // q_u
             Bsrc = P + (size_t)(1*16 + bh) * 65536; }    // k_u
  int lane = t & 63, l16 = lane & 15, quad = lane >> 4;
  int w = t >> 6, wm = w >> 1, wn = w & 1;
  int srow = lane >> 2, scol = (lane & 3) * 8;
  const unsigned short* gA = Asrc + (size_t)(R0 + w*32 + srow) * 64 + scol;
  const unsigned short* gB = Bsrc + (size_t)(C0 + w*32 + srow) * 64 + scol;
  unsigned short* lA = sA + (w*32) * 32;
  unsigned short* lB = sB + (w*32) * 32;
  f32x4 acc[4][4] = {};
#pragma unroll
  for (int k0 = 0; k0 < 64; k0 += 32){
    GLL(gA + k0,           lA);
    GLL(gA + k0 + 16*64,   lA + 16*32);
    GLL(gB + k0,           lB);
    GLL(gB + k0 + 16*64,   lB + 16*32);
    __syncthreads();
    bf16x8 af[4], bfr[4];
#pragma unroll
    for (int mi = 0; mi < 4; ++mi)
      af[mi] = *(const bf16x8*)(sA + (wm*64 + mi*16 + l16) * 32 + quad * 8);
#pragma unroll
    for (int fi = 0; fi < 4; ++fi)
      bfr[fi] = *(const bf16x8*)(sB + (wn*64 + fi*16 + l16) * 32 + quad * 8);
#pragma unroll
    for (int fi = 0; fi < 4; ++fi)
#pragma unroll
      for (int mi = 0; mi < 4; ++mi)
        acc[fi][mi] = mfma16(bfr[fi], af[mi], acc[fi][mi]);
    __syncthreads();
  }
  unsigned short* out = (mat ? sig : term1) + (size_t)bh * 1048576;
#pragma unroll
  for (int fi = 0; fi < 4; ++fi)
#pragma unroll
    for (int mi = 0; mi < 4; ++mi){
      int row = R0 + wm*64 + mi*16 + l16;
      int c0 = C0 + wn*64 + fi*16 + quad*4;
      ushort4 o;
#pragma unroll
      for (int r = 0; r < 4; ++r){
        int col = c0 + r;
        float v = acc[fi][mi][r] * SCALE;
        unsigned short res;
        if (!mat) res = (col <= row) ? f2bf(v) : (unsigned short)0;
        else      res = (col >  row) ? f2bf(1.f / (1.f + expf(-v))) : (unsigned short)0;
        ((unsigned short*)&o)[r] = res;
      }
      *(ushort4*)(out + (size_t)row * 1024 + c0) = o;
    }
}

// ---------------- K3: finb(bf16) = S_c - silu(S_u), lower tiles only --------
__global__ __launch_bounds__(256) void k_scores(
    const unsigned short* __restrict__ P, const unsigned short* __restrict__ term1,
    const unsigned short* __restrict__ sig, unsigned short* __restrict__ finb){
  __shared__ unsigned short sA[128 * 32], sB[128 * 32];
  int t = threadIdx.x;
  int bh = blockIdx.x & 15, tt = blockIdx.x >> 4;
  int ti = SC_TI[tt], tj = SC_TJ[tt];
  int delta = ti - tj;
  int M0 = ti * 128, N0 = tj * 128;
  size_t sbase = (size_t)bh * 1048576;
  int lane = t & 63, l16 = lane & 15, quad = lane >> 4;
  int w = t >> 6, wm = w >> 1, wn = w & 1;
  int srow = (lane >> 2), scol = (lane & 3) * 8;
  unsigned short* lA = sA + (w*32) * 32;
  unsigned short* lB = sB + (w*32) * 32;
  f32x4 acc_u[4][4] = {};
  f32x4 acc_c[4][4] = {};
  {
    const unsigned short* gA = term1 + sbase + (size_t)(M0 + w*32 + srow) * 1024 + scol;
    const unsigned short* gB = sig   + sbase + (size_t)(N0 + w*32 + srow) * 1024 + scol;
    int steps = (delta + 1) * 4;
    for (int s = 0; s < steps; ++s){
      int j0 = N0 + s * 32;
      GLL(gA + j0,             lA);
      GLL(gA + j0 + 16*1024,   lA + 16*32);
      GLL(gB + j0,             lB);
      GLL(gB + j0 + 16*1024,   lB + 16*32);
      __syncthreads();
      bf16x8 af[4], bfr[4];
#pragma unroll
      for (int mi = 0; mi < 4; ++mi)
        af[mi] = *(const bf16x8*)(sA + (wm*64 + mi*16 + l16) * 32 + quad * 8);
#pragma unroll
      for (int fi = 0; fi < 4; ++fi)
        bfr[fi] = *(const bf16x8*)(sB + (wn*64 + fi*16 + l16) * 32 + quad * 8);
#pragma unroll
      for (int fi = 0; fi < 4; ++fi)
#pragma unroll
        for (int mi = 0; mi < 4; ++mi)
          acc_u[fi][mi] = mfma16(bfr[fi], af[mi], acc_u[fi][mi]);
      __syncthreads();
    }
  }
  {
    const unsigned short* Qc = P + (size_t)(3*16 + bh) * 65536;
    const unsigned short* Kc = P + (size_t)(4*16 + bh) * 65536;
#pragma unroll
    for (int k0 = 0; k0 < 64; k0 += 32){
      bf16x8 af[4], bfr[4];
#pragma unroll
      for (int mi = 0; mi < 4; ++mi)
        af[mi] = ld8(Qc + (size_t)(M0 + wm*64 + mi*16 + l16) * 64 + k0 + quad * 8);
#pragma unroll
      for (int fi = 0; fi < 4; ++fi)
        bfr[fi] = ld8(Kc + (size_t)(N0 + wn*64 + fi*16 + l16) * 64 + k0 + quad * 8);
#pragma unroll
      for (int fi = 0; fi < 4; ++fi)
#pragma unroll
        for (int mi = 0; mi < 4; ++mi)
          acc_c[fi][mi] = mfma16(bfr[fi], af[mi], acc_c[fi][mi]);
    }
  }
  unsigned short* out = finb + sbase;
#pragma unroll
  for (int fi = 0; fi < 4; ++fi)
#pragma unroll
    for (int mi = 0; mi < 4; ++mi){
      int row = M0 + wm*64 + mi*16 + l16;
      int c0 = N0 + wn*64 + fi*16 + quad*4;
      ushort4 o;
#pragma unroll
      for (int r = 0; r < 4; ++r){
        float su = acc_u[fi][mi][r];
        float v = acc_c[fi][mi][r] * SCALE - su / (1.f + expf(-su));
        ((unsigned short*)&o)[r] = f2bf(v);   // col>row masked downstream
      }
      *(ushort4*)(out + (size_t)row * 1024 + c0) = o;
    }
}

// ---------------- K4: fused softmax + PV; snake mt map; O2 [2048][512] ------
__global__ __launch_bounds__(256) void k_pv_soft(
    const unsigned short* __restrict__ finb, const unsigned short* __restrict__ vcT,
    unsigned short* __restrict__ O2){
  __shared__ __align__(16) unsigned char smem[16 * 1032 * 2];  // 33 KB
  unsigned short* lp = (unsigned short*)smem;                  // probs [16][1032]
  float* red = (float*)smem;                                   // overlay
  int t = threadIdx.x;
  int bh = blockIdx.x & 15;
  int r4 = blockIdx.x >> 8, g = (blockIdx.x >> 4) & 15;
  // snake: CU-group g gets mts {63-g, 32+g, 31-g, g} -> work-sum 126 const
  int mt = (r4 == 0) ? 63 - g : (r4 == 1) ? 32 + g : (r4 == 2) ? 31 - g : g;
  int m0 = mt * 16;
  int kceil = ((m0 + 16 + 31) >> 5) << 5;                      // mult of 32
  {
    int rl = t >> 4, sub = t & 15;
    int rloc = m0 + rl;
    const unsigned short* p = finb + (size_t)bh * 1048576 + (size_t)rloc * 1024;
    float v[8][8];
    float m = -INFINITY;
#pragma unroll
    for (int i = 0; i < 8; ++i){
      int c8 = (sub + 16*i) * 8;
      if (c8 < kceil){
        ushort4 u0 = *(const ushort4*)(p + c8);
        ushort4 u1 = *(const ushort4*)(p + c8 + 4);
        float vv[8] = {bf2f(u0.x), bf2f(u0.y), bf2f(u0.z), bf2f(u0.w),
                       bf2f(u1.x), bf2f(u1.y), bf2f(u1.z), bf2f(u1.w)};
#pragma unroll
        for (int e = 0; e < 8; ++e){
          v[i][e] = (c8 + e <= rloc) ? vv[e] : -INFINITY;
          m = fmaxf(m, v[i][e]);
        }
      }
    }
#pragma unroll
    for (int off = 1; off < 16; off <<= 1) m = fmaxf(m, __shfl_xor(m, off));
    float s = 0.f;
#pragma unroll
    for (int i = 0; i < 8; ++i){
      int c8 = (sub + 16*i) * 8;
      if (c8 < kceil){
#pragma unroll
        for (int e = 0; e < 8; ++e){
          v[i][e] = expf(v[i][e] - m);
          s += v[i][e];
        }
      }
    }
#pragma unroll
    for (int off = 1; off < 16; off <<= 1) s += __shfl_xor(s, off);
    float inv = 1.f / s;
#pragma unroll
    for (int i = 0; i < 8; ++i){
      int c8 = (sub + 16*i) * 8;
      if (c8 < kceil){
        ushort4 o0, o1;
        o0.x = f2bf(v[i][0] * inv); o0.y = f2bf(v[i][1] * inv);
        o0.z = f2bf(v[i][2] * inv); o0.w = f2bf(v[i][3] * inv);
        o1.x = f2bf(v[i][4] * inv); o1.y = f2bf(v[i][5] * inv);
        o1.z = f2bf(v[i][6] * inv); o1.w = f2bf(v[i][7] * inv);
        *(ushort4*)(lp + rl * 1032 + c8) = o0;
        *(ushort4*)(lp + rl * 1032 + c8 + 4) = o1;
      }
    }
  }
  __syncthreads();
  int lane = t & 63, l16 = lane & 15, quad = lane >> 4, w = t >> 6;
  const unsigned short* Bt = vcT + (size_t)bh * 65536;
  int ktot = kceil >> 5;
  int per = (ktot + 3) >> 2;
  int s0 = w * per, s1 = min(s0 + per, ktot);
  f32x4 acc[4] = {};
  for (int s = s0; s < s1; ++s){
    int k0 = s * 32;
    bf16x8 a = *(const bf16x8*)(lp + l16 * 1032 + k0 + quad * 8);
#pragma unroll
    for (int fi = 0; fi < 4; ++fi){
      bf16x8 b = ld8(Bt + (size_t)(fi*16 + l16) * 1024 + k0 + quad * 8);
      acc[fi] = mfma16(a, b, acc[fi]);
    }
  }
  __syncthreads();
#pragma unroll
  for (int fi = 0; fi < 4; ++fi)
#pragma unroll
    for (int r = 0; r < 4; ++r)
      red[w * 1024 + (quad*4 + r) * 64 + fi*16 + l16] = acc[fi][r];
  __syncthreads();
  float4 a0 = ((const float4*)(red + 0*1024))[t];
  float4 a1 = ((const float4*)(red + 1*1024))[t];
  float4 a2 = ((const float4*)(red + 2*1024))[t];
  float4 a3 = ((const float4*)(red + 3*1024))[t];
  ushort4 o;
  o.x = f2bf(a0.x + a1.x + a2.x + a3.x);
  o.y = f2bf(a0.y + a1.y + a2.y + a3.y);
  o.z = f2bf(a0.z + a1.z + a2.z + a3.z);
  o.w = f2bf(a0.w + a1.w + a2.w + a3.w);
  int e = t * 4, row = e >> 6, col = e & 63;
  int b_ = bh >> 3, h_ = bh & 7;
  *(ushort4*)(O2 + (size_t)(b_*1024 + m0 + row) * 512 + h_*64 + col) = o;
}

// ---------------- K5: out(f32) = O_cat @ w_out (contiguous A reads) ---------
__global__ __launch_bounds__(256) void k_out(
    const unsigned short* __restrict__ O2, const unsigned short* __restrict__ woT,
    float* __restrict__ out){
  __shared__ float red[4][1024];
  int t = threadIdx.x, lane = t & 63, l16 = lane & 15, quad = lane >> 4, w = t >> 6;
  int mt = blockIdx.x >> 3, nt = blockIdx.x & 7;
  int m0 = mt * 16, n0 = nt * 64;
  int r_ = m0 + l16;
  f32x4 acc[4] = {};
#pragma unroll
  for (int s = 0; s < 4; ++s){
    int kk = w * 128 + s * 32 + quad * 8;
    bf16x8 a = ld8(O2 + (size_t)r_ * 512 + kk);
#pragma unroll
    for (int fi = 0; fi < 4; ++fi){
      bf16x8 b = ld8(woT + (size_t)(n0 + fi*16 + l16) * 512 + kk);
      acc[fi] = mfma16(a, b, acc[fi]);
    }
  }
#pragma unroll
  for (int fi = 0; fi < 4; ++fi)
#pragma unroll
    for (int r = 0; r < 4; ++r)
      red[w][(quad*4 + r) * 64 + fi*16 + l16] = acc[fi][r];
  __syncthreads();
  float4 a0 = ((const float4*)red[0])[t];
  float4 a1 = ((const float4*)red[1])[t];
  float4 a2 = ((const float4*)red[2])[t];
  float4 a3 = ((const float4*)red[3])[t];
  float4 o;
  o.x = a0.x + a1.x + a2.x + a3.x;
  o.y = a0.y + a1.y + a2.y + a3.y;
  o.z = a0.z + a1.z + a2.z + a3.z;
  o.w = a0.w + a1.w + a2.w + a3.w;
  int e = t * 4, row = e >> 6, col = e & 63;
  *(float4*)(out + (size_t)(m0 + row) * 512 + n0 + col) = o;
}

extern "C" void kernel_launch(void* const* d_in, const int* in_sizes, int n_in,
                              void* d_out, int out_size, void* d_ws, size_t ws_size,
                              hipStream_t stream){
  const float* x = (const float*)d_in[0];
  float* out = (float*)d_out;
  unsigned short* ws = (unsigned short*)d_ws;

  unsigned short* wT    = ws;                                   // 7*262144
  unsigned short* xb    = wT    + (size_t)7  * 262144;          // 1048576
  unsigned short* P     = xb    + (size_t)1048576;              // 96*65536
  unsigned short* vcT   = P     + (size_t)96 * 65536;           // 16*65536
  unsigned short* term1 = vcT   + (size_t)16 * 65536;           // 16*1048576
  unsigned short* sig   = term1 + (size_t)16 * 1048576;         // 16*1048576
  unsigned short* O2    = sig   + (size_t)16 * 1048576;         // 16*65536 ([2048][512])
  unsigned short* finb  = O2    + (size_t)16 * 65536;           // 16*1048576 bf16

  k_prep<<<1472, 256, 0, stream>>>(
      x,
      (const float*)d_in[1], (const float*)d_in[2], (const float*)d_in[3],
      (const float*)d_in[4], (const float*)d_in[5], (const float*)d_in[6],
      (const float*)d_in[7], xb, wT);
  k_proj<<<768, 256, 0, stream>>>(xb, wT, P);
  k_qk_vct<<<1408, 256, 0, stream>>>(P, term1, sig, vcT);
  k_scores<<<576, 256, 0, stream>>>(P, term1, sig, finb);
  k_pv_soft<<<1024, 256, 0, stream>>>(finb, vcT, O2);
  k_out<<<1024, 256, 0, stream>>>(O2, wT + (size_t)6 * 262144, out);
}